// Round 1
// baseline (5685.706 us; speedup 1.0000x reference)
//
#include <hip/hip_runtime.h>
#include <hip/hip_bf16.h>
#include <math.h>

// Problem constants
#define NN 40000
#define EE 640000
#define BB 8192
#define IN_DIM 768
#define META_DIM 6
#define XDIM 774      // IN+META
#define HID 256
#define OUT_D 128
#define NEXP 4
#define NET_T 3
#define REL_D 200
#define NLAY 4
#define FF_D 512

// ---------------------------------------------------------------------------
// Generic tiled fp32 GEMM: C[M,Nn] = act(A[M,K(lda)] @ B[Nn,K]^T + bias + res)
// ACT: 0=none, 1=relu, 2=elu (with residual)
// Block 256 threads, tile 64x64, K-tile 16, 4x4 micro-tile per thread.
// ---------------------------------------------------------------------------
template<int ACT>
__global__ void gemm_kernel(const float* __restrict__ A, int lda,
                            const float* __restrict__ Bw,
                            const float* __restrict__ bias,
                            const float* __restrict__ res,
                            float* __restrict__ C, int M, int Nn, int K)
{
    __shared__ float As[16][68];
    __shared__ float Bs[16][68];
    int bm = blockIdx.y * 64, bn = blockIdx.x * 64;
    int t = threadIdx.x;
    int tx = t & 15, ty = t >> 4;
    float acc[4][4] = {{0.f}};

    for (int k0 = 0; k0 < K; k0 += 16) {
#pragma unroll
        for (int i = 0; i < 4; i++) {
            int l = t * 4 + i; int mm = l >> 4, kk = l & 15;
            int gm = bm + mm, gk = k0 + kk;
            As[kk][mm] = (gm < M && gk < K) ? A[(size_t)gm * lda + gk] : 0.f;
        }
#pragma unroll
        for (int i = 0; i < 4; i++) {
            int l = t * 4 + i; int nn = l >> 4, kk = l & 15;
            int gn = bn + nn, gk = k0 + kk;
            Bs[kk][nn] = (gn < Nn && gk < K) ? Bw[(size_t)gn * K + gk] : 0.f;
        }
        __syncthreads();
#pragma unroll
        for (int kk = 0; kk < 16; kk++) {
            float4 a4 = *reinterpret_cast<const float4*>(&As[kk][ty * 4]);
            float4 b4 = *reinterpret_cast<const float4*>(&Bs[kk][tx * 4]);
            float a0[4] = {a4.x, a4.y, a4.z, a4.w};
            float b0[4] = {b4.x, b4.y, b4.z, b4.w};
#pragma unroll
            for (int i = 0; i < 4; i++)
#pragma unroll
                for (int j = 0; j < 4; j++)
                    acc[i][j] += a0[i] * b0[j];
        }
        __syncthreads();
    }
#pragma unroll
    for (int i = 0; i < 4; i++) {
        int gm = bm + ty * 4 + i; if (gm >= M) continue;
#pragma unroll
        for (int j = 0; j < 4; j++) {
            int gn = bn + tx * 4 + j; if (gn >= Nn) continue;
            float v = acc[i][j];
            if (bias) v += bias[gn];
            if (res)  v += res[(size_t)gm * Nn + gn];
            if (ACT == 1) v = fmaxf(v, 0.f);
            else if (ACT == 2) v = (v > 0.f) ? v : expm1f(v);
            C[(size_t)gm * Nn + gn] = v;
        }
    }
}

static void launch_gemm(int act, const float* A, int lda, const float* Bw,
                        const float* bias, const float* res, float* C,
                        int M, int Nn, int K, hipStream_t s)
{
    dim3 grid((Nn + 63) / 64, (M + 63) / 64);
    dim3 blk(256);
    if (act == 0)      gemm_kernel<0><<<grid, blk, 0, s>>>(A, lda, Bw, bias, res, C, M, Nn, K);
    else if (act == 1) gemm_kernel<1><<<grid, blk, 0, s>>>(A, lda, Bw, bias, res, C, M, Nn, K);
    else               gemm_kernel<2><<<grid, blk, 0, s>>>(A, lda, Bw, bias, res, C, M, Nn, K);
}

// ---------------------------------------------------------------------------
// GNN helper kernels
// ---------------------------------------------------------------------------
__device__ __forceinline__ unsigned fenc(float f) {
    unsigned b = __float_as_uint(f);
    return (b & 0x80000000u) ? ~b : (b | 0x80000000u);
}
__device__ __forceinline__ float fdec(unsigned u) {
    unsigned b = (u & 0x80000000u) ? (u & 0x7FFFFFFFu) : ~u;
    return __uint_as_float(b);
}

// s_i[m] = Wx[m]·a[0:256], s_j[m] = Wx[m]·a[256:512]; wave per row
__global__ void sisj_kernel(const float* __restrict__ Wx, const float* __restrict__ a,
                            float* __restrict__ s_i, float* __restrict__ s_j, int n)
{
    int t = threadIdx.x; int w = t >> 6, l = t & 63;
    int m = blockIdx.x * 4 + w; if (m >= n) return;
    const float* r = Wx + (size_t)m * HID;
    float v1 = 0.f, v2 = 0.f;
#pragma unroll
    for (int i = 0; i < 4; i++) {
        float xv = r[l + 64 * i];
        v1 += xv * a[l + 64 * i];
        v2 += xv * a[HID + l + 64 * i];
    }
    for (int off = 32; off; off >>= 1) { v1 += __shfl_down(v1, off); v2 += __shfl_down(v2, off); }
    if (l == 0) { s_i[m] = v1; s_j[m] = v2; }
}

// rs[t] = a3 · (Wr @ rel[t]); block per relation type
__global__ void rs_kernel(const float* __restrict__ Wr, const float* __restrict__ rel,
                          const float* __restrict__ a3, float* __restrict__ rs)
{
    __shared__ float red[256];
    int tt = blockIdx.x; int j = threadIdx.x;
    const float* relr = rel + tt * REL_D;
    const float* wr = Wr + (size_t)j * REL_D;
    float wsum = 0.f;
    for (int k = 0; k < REL_D; k++) wsum += wr[k] * relr[k];
    red[j] = wsum * a3[j];
    __syncthreads();
    for (int s2 = 128; s2; s2 >>= 1) { if (j < s2) red[j] += red[j + s2]; __syncthreads(); }
    if (j == 0) rs[tt] = red[0];
}

__global__ void edge_logit_kernel(const int* __restrict__ src, const int* __restrict__ dst,
                                  const int* __restrict__ et, const float* __restrict__ s_i,
                                  const float* __restrict__ s_j, const float* __restrict__ rs,
                                  float* __restrict__ logit)
{
    int e = blockIdx.x * blockDim.x + threadIdx.x;
    if (e >= EE) return;
    float v = s_i[dst[e]] + s_j[src[e]] + rs[et[e]];
    logit[e] = (v >= 0.f) ? v : 0.2f * v;
}

__global__ void fill_u32_kernel(unsigned* __restrict__ p, unsigned v, int n)
{
    int i = blockIdx.x * blockDim.x + threadIdx.x;
    if (i < n) p[i] = v;
}

__global__ void seg_max_kernel(const int* __restrict__ dst, const float* __restrict__ logit,
                               unsigned* __restrict__ segmax)
{
    int e = blockIdx.x * blockDim.x + threadIdx.x;
    if (e >= EE) return;
    atomicMax(&segmax[dst[e]], fenc(logit[e]));
}

__global__ void seg_expsum_kernel(const int* __restrict__ dst, const float* __restrict__ logit,
                                  const unsigned* __restrict__ segmax,
                                  float* __restrict__ evals, float* __restrict__ segsum)
{
    int e = blockIdx.x * blockDim.x + threadIdx.x;
    if (e >= EE) return;
    int dd = dst[e];
    float ev = expf(logit[e] - fdec(segmax[dd]));
    evals[e] = ev;
    atomicAdd(&segsum[dd], ev);
}

__global__ void alpha_kernel(const int* __restrict__ dst, float* __restrict__ evals,
                             const float* __restrict__ segsum)
{
    int e = blockIdx.x * blockDim.x + threadIdx.x;
    if (e >= EE) return;
    evals[e] = evals[e] / (segsum[dst[e]] + 1e-16f);
}

// agg[dst] += Wx[src] * alpha; wave per edge, 4 dims/lane
__global__ void scatter_agg_kernel(const int* __restrict__ src, const int* __restrict__ dst,
                                   const float* __restrict__ alpha, const float* __restrict__ Wx,
                                   float* __restrict__ agg)
{
    int t = threadIdx.x; int w = t >> 6, l = t & 63;
    int e = blockIdx.x * 4 + w;
    if (e >= EE) return;
    int s = src[e], dd = dst[e];
    float al = alpha[e];
    const float* wr = Wx + (size_t)s * HID;
    float* ar = agg + (size_t)dd * HID;
#pragma unroll
    for (int i = 0; i < 4; i++)
        atomicAdd(&ar[l + 64 * i], wr[l + 64 * i] * al);
}

__global__ void rownorm_kernel(float* __restrict__ h, int n)
{
    int t = threadIdx.x; int w = t >> 6, l = t & 63;
    int m = blockIdx.x * 4 + w; if (m >= n) return;
    float* r = h + (size_t)m * HID;
    float vals[4]; float q = 0.f;
#pragma unroll
    for (int i = 0; i < 4; i++) { vals[i] = r[l + 64 * i]; q += vals[i] * vals[i]; }
    for (int off = 32; off; off >>= 1) q += __shfl_down(q, off);
    q = __shfl(q, 0);
    float inv = 1.f / fmaxf(sqrtf(q), 1e-12f);
#pragma unroll
    for (int i = 0; i < 4; i++) r[l + 64 * i] = vals[i] * inv;
}

// ---------------------------------------------------------------------------
// MoE gating: wave per batch row. Computes comb (= masked softmax L) and
// per-expert batch sums (for the load-balance loss).
// ---------------------------------------------------------------------------
__global__ void moe_gate_kernel(const float* __restrict__ xv, const float* __restrict__ gate_w,
                                const float* __restrict__ noise_w, const float* __restrict__ eps,
                                float* __restrict__ comb, float* __restrict__ tmpsum)
{
    __shared__ float part[4];
    int t = threadIdx.x; int w = t >> 6, l = t & 63;
    if (t < 4) part[t] = 0.f;
    __syncthreads();
    int b = blockIdx.x * 4 + w;
    const float* xr = xv + (size_t)b * OUT_D;
    float x0 = xr[l], x1 = xr[l + 64];
    float dots[5];
#pragma unroll
    for (int e = 0; e < 4; e++) {
        const float* gw = gate_w + e * OUT_D;
        float v = x0 * gw[l] + x1 * gw[l + 64];
        for (int off = 32; off; off >>= 1) v += __shfl_down(v, off);
        dots[e] = v;
    }
    {
        float v = x0 * noise_w[l] + x1 * noise_w[l + 64];
        for (int off = 32; off; off >>= 1) v += __shfl_down(v, off);
        dots[4] = v;
    }
    if (l == 0) {
        float xg = dots[4];
        float nsd = (xg > 20.f) ? xg : log1pf(expf(xg));
        float hv[4];
#pragma unroll
        for (int e = 0; e < 4; e++) hv[e] = dots[e] + eps[(size_t)b * 4 + e] * nsd;
        // bottom-2 (ties -> lower index), matching top_k(-h, 2)
        int i1 = 0;
        for (int e = 1; e < 4; e++) if (hv[e] < hv[i1]) i1 = e;
        int i2 = -1;
        for (int e = 0; e < 4; e++) { if (e == i1) continue; if (i2 < 0 || hv[e] < hv[i2]) i2 = e; }
        int k1 = -1, k2 = -1;
        for (int e = 0; e < 4; e++) { if (e != i1 && e != i2) { if (k1 < 0) k1 = e; else k2 = e; } }
        float m = fmaxf(hv[k1], hv[k2]);
        float e1 = expf(hv[k1] - m), e2 = expf(hv[k2] - m);
        float s = e1 + e2;
        float L[4] = {0.f, 0.f, 0.f, 0.f};
        L[k1] = e1 / s; L[k2] = e2 / s;
#pragma unroll
        for (int e = 0; e < 4; e++) comb[(size_t)b * 4 + e] = L[e];
        atomicAdd(&part[k1], L[k1]);
        atomicAdd(&part[k2], L[k2]);
    }
    __syncthreads();
    if (t < 4) atomicAdd(&tmpsum[t], part[t]);
}

// out z[b, view, :] = sum_e comb[b,e] * eo[e,b,:]
__global__ void moe_combine_kernel(const float* __restrict__ eo, const float* __restrict__ comb,
                                   float* __restrict__ zout)
{
    int idx = blockIdx.x * blockDim.x + threadIdx.x;
    if (idx >= BB * OUT_D) return;
    int b = idx >> 7, o = idx & 127;
    const size_t S = (size_t)BB * OUT_D;
    float v = comb[b * 4 + 0] * eo[idx] + comb[b * 4 + 1] * eo[idx + S]
            + comb[b * 4 + 2] * eo[idx + 2 * S] + comb[b * 4 + 3] * eo[idx + 3 * S];
    zout[(size_t)b * (3 * OUT_D) + o] = v;
}

__global__ void loss_kernel(const float* __restrict__ tmpsum, float* __restrict__ out)
{
    if (threadIdx.x == 0 && blockIdx.x == 0) {
        float total = 0.f;
        for (int v = 0; v < 3; v++) {
            const float* tp = tmpsum + v * 4;
            float mean = (tp[0] + tp[1] + tp[2] + tp[3]) * 0.25f;
            float var = 0.f;
            for (int e = 0; e < 4; e++) { float d = tp[e] - mean; var += d * d; }
            var /= 3.f;  // ddof=1
            float r = sqrtf(var) / mean;
            total += r * r;
        }
        out[0] = total;
    }
}

// ---------------------------------------------------------------------------
// Transformer: tiny attention (S=3, hd=32), half-wave per (b, head)
// ---------------------------------------------------------------------------
__global__ void attn_kernel(const float* __restrict__ qkv, float* __restrict__ o)
{
    int t = threadIdx.x;
    int half = t >> 5;
    int d = t & 31;
    int task = blockIdx.x * 8 + half;   // b*4 + h, total 32768
    int b = task >> 2, h = task & 3;
    const float* base = qkv + (size_t)b * 3 * 384 + h * 32;
    float q0 = base[d],       q1 = base[384 + d],       q2 = base[768 + d];
    float k0 = base[128 + d], k1 = base[384 + 128 + d], k2 = base[768 + 128 + d];
    float v0 = base[256 + d], v1 = base[384 + 256 + d], v2 = base[768 + 256 + d];
    float s[3][3];
    s[0][0] = q0 * k0; s[0][1] = q0 * k1; s[0][2] = q0 * k2;
    s[1][0] = q1 * k0; s[1][1] = q1 * k1; s[1][2] = q1 * k2;
    s[2][0] = q2 * k0; s[2][1] = q2 * k1; s[2][2] = q2 * k2;
#pragma unroll
    for (int i = 0; i < 3; i++)
#pragma unroll
        for (int j = 0; j < 3; j++) {
            float v = s[i][j];
            for (int off = 16; off; off >>= 1) v += __shfl_xor(v, off, 32);
            s[i][j] = v;
        }
    const float scale = 0.17677669529663687f;  // 1/sqrt(32)
    float outv[3];
#pragma unroll
    for (int i = 0; i < 3; i++) {
        float a0 = s[i][0] * scale, a1 = s[i][1] * scale, a2 = s[i][2] * scale;
        float m = fmaxf(a0, fmaxf(a1, a2));
        float e0 = expf(a0 - m), e1 = expf(a1 - m), e2 = expf(a2 - m);
        float inv = 1.f / (e0 + e1 + e2);
        outv[i] = (e0 * v0 + e1 * v1 + e2 * v2) * inv;
    }
    float* ob = o + (size_t)b * 3 * 128 + h * 32;
    ob[d] = outv[0]; ob[128 + d] = outv[1]; ob[256 + d] = outv[2];
}

// x = LN(x + add) * g + b; rows of 128, wave per row, in-place on x
__global__ void ln_residual_kernel(float* __restrict__ x, const float* __restrict__ add,
                                   const float* __restrict__ g, const float* __restrict__ bta, int M)
{
    int t = threadIdx.x; int w = t >> 6, l = t & 63;
    int row = blockIdx.x * 4 + w; if (row >= M) return;
    float* xr = x + (size_t)row * 128;
    const float* ar = add + (size_t)row * 128;
    float v0 = xr[l] + ar[l], v1 = xr[l + 64] + ar[l + 64];
    float s = v0 + v1;
    for (int off = 32; off; off >>= 1) s += __shfl_down(s, off);
    s = __shfl(s, 0);
    float mu = s * (1.f / 128.f);
    float d0 = v0 - mu, d1 = v1 - mu;
    float q = d0 * d0 + d1 * d1;
    for (int off = 32; off; off >>= 1) q += __shfl_down(q, off);
    q = __shfl(q, 0);
    float inv = rsqrtf(q * (1.f / 128.f) + 1e-5f);
    xr[l]      = d0 * inv * g[l] + bta[l];
    xr[l + 64] = d1 * inv * g[l + 64] + bta[l + 64];
}

// ---------------------------------------------------------------------------
// Orchestration
// ---------------------------------------------------------------------------
extern "C" void kernel_launch(void* const* d_in, const int* in_sizes, int n_in,
                              void* d_out, int out_size, void* d_ws, size_t ws_size,
                              hipStream_t stream)
{
    const float* x         = (const float*)d_in[0];
    const float* noise     = (const float*)d_in[1];
    const float* g_lin1_w  = (const float*)d_in[2];
    const float* g_lin1_b  = (const float*)d_in[3];
    const float* conv_W    = (const float*)d_in[4];
    const float* conv_Wr   = (const float*)d_in[5];
    const float* conv_a    = (const float*)d_in[6];
    const float* conv_Wres = (const float*)d_in[7];
    const float* conv_rel  = (const float*)d_in[8];
    const float* g_lin2_w  = (const float*)d_in[9];
    const float* g_lin2_b  = (const float*)d_in[10];
    const float* te_w      = (const float*)d_in[11];
    const float* te_b      = (const float*)d_in[12];
    const float* me_w1     = (const float*)d_in[13];
    const float* me_b1     = (const float*)d_in[14];
    const float* me_w2     = (const float*)d_in[15];
    const float* me_b2     = (const float*)d_in[16];
    const float* moe_gate_w  = (const float*)d_in[17];
    const float* moe_noise_w = (const float*)d_in[18];
    const float* moe_w1    = (const float*)d_in[19];
    const float* moe_b1    = (const float*)d_in[20];
    const float* moe_w2    = (const float*)d_in[21];
    const float* moe_b2    = (const float*)d_in[22];
    const float* tf_qkv_w  = (const float*)d_in[23];
    const float* tf_qkv_b  = (const float*)d_in[24];
    const float* tf_out_w  = (const float*)d_in[25];
    const float* tf_out_b  = (const float*)d_in[26];
    const float* tf_ln1_g  = (const float*)d_in[27];
    const float* tf_ln1_b  = (const float*)d_in[28];
    const float* tf_ff1_w  = (const float*)d_in[29];
    const float* tf_ff1_b  = (const float*)d_in[30];
    const float* tf_ff2_w  = (const float*)d_in[31];
    const float* tf_ff2_b  = (const float*)d_in[32];
    const float* tf_ln2_g  = (const float*)d_in[33];
    const float* tf_ln2_b  = (const float*)d_in[34];
    const float* clf_w     = (const float*)d_in[35];
    const float* clf_b     = (const float*)d_in[36];
    const int*   edge_index = (const int*)d_in[37];
    const int*   edge_type  = (const int*)d_in[38];

    float* ws = (float*)d_ws;

    // Arena (floats), phase-reused:
    //  A: h0 / h2(layer2 out) / qkv           10,240,000
    //  B: wx / graph / ff1                    12,582,912
    //  C: agg / (h1buf+eo) / (attn_o+tmp1)    10,240,000
    //  D: h1out / (z + x_t + x_mh + x_m)      10,240,000
    const size_t F_A = 0;
    const size_t F_B = 10240000;
    const size_t F_C = F_B + 12582912;
    const size_t F_D = F_C + 10240000;
    const size_t F_M = F_D + 10240000;

    float* h0     = ws + F_A;
    float* qkv    = ws + F_A;
    float* wx     = ws + F_B;
    float* graph  = ws + F_B;
    float* ff1    = ws + F_B;
    float* agg    = ws + F_C;
    float* h1buf  = ws + F_C;
    float* eo     = ws + F_C + 4194304;
    float* attn_o = ws + F_C;
    float* tmp1   = ws + F_C + 3200000;
    float* hl1    = ws + F_D;
    float* z      = ws + F_D;
    float* x_t    = ws + F_D + 3200000;
    float* x_mh   = ws + F_D + 4300000;
    float* x_m    = ws + F_D + 6500000;

    float* s_i    = ws + F_M;
    float* s_j    = ws + F_M + 40000;
    unsigned* segmax_u = (unsigned*)(ws + F_M + 80000);
    float* segsum = ws + F_M + 120000;
    float* logit  = ws + F_M + 160000;
    float* evals  = ws + F_M + 800000;
    float* rs     = ws + F_M + 1440000;
    float* comb   = ws + F_M + 1440016;
    float* tmpsum = ws + F_M + 1472784;

    const int* srcv = edge_index;
    const int* dstv = edge_index + EE;

    // ---- 1. h = relu(x @ g_lin1_w.T + b) ----
    launch_gemm(1, x, XDIM, g_lin1_w, g_lin1_b, nullptr, h0, NN, HID, XDIM, stream);

    // ---- 2. two HGN layers ----
    float* hin = h0;
    float* hout = hl1;
    for (int layer = 0; layer < 2; layer++) {
        const float* W    = conv_W    + (size_t)layer * HID * HID;
        const float* Wr   = conv_Wr   + (size_t)layer * HID * REL_D;
        const float* a    = conv_a    + (size_t)layer * 3 * HID;
        const float* Wres = conv_Wres + (size_t)layer * HID * HID;
        const float* rel  = conv_rel  + (size_t)layer * NET_T * REL_D;

        launch_gemm(0, hin, HID, W, nullptr, nullptr, wx, NN, HID, HID, stream);
        sisj_kernel<<<NN / 4, 256, 0, stream>>>(wx, a, s_i, s_j, NN);
        rs_kernel<<<NET_T, 256, 0, stream>>>(Wr, rel, a + 2 * HID, rs);
        edge_logit_kernel<<<EE / 256, 256, 0, stream>>>(srcv, dstv, edge_type, s_i, s_j, rs, logit);
        fill_u32_kernel<<<(NN + 255) / 256, 256, 0, stream>>>(segmax_u, 0x007FFFFFu, NN);
        seg_max_kernel<<<EE / 256, 256, 0, stream>>>(dstv, logit, segmax_u);
        hipMemsetAsync(segsum, 0, NN * sizeof(float), stream);
        seg_expsum_kernel<<<EE / 256, 256, 0, stream>>>(dstv, logit, segmax_u, evals, segsum);
        alpha_kernel<<<EE / 256, 256, 0, stream>>>(dstv, evals, segsum);
        hipMemsetAsync(agg, 0, (size_t)NN * HID * sizeof(float), stream);
        scatter_agg_kernel<<<EE / 4, 256, 0, stream>>>(srcv, dstv, evals, wx, agg);
        // out = elu(agg + h @ Wres.T)
        launch_gemm(2, hin, HID, Wres, nullptr, agg, hout, NN, HID, HID, stream);
        if (layer == 1) rownorm_kernel<<<NN / 4, 256, 0, stream>>>(hout, NN);
        float* t2 = hin; hin = hout; hout = t2;
    }
    float* h2 = hin;  // = bufA

    // ---- 3. graph = relu(h2 @ g_lin2.T + b) ----
    launch_gemm(1, h2, HID, g_lin2_w, g_lin2_b, nullptr, graph, NN, OUT_D, HID, stream);

    // ---- 4. view encoders ----
    launch_gemm(1, x, XDIM, te_w, te_b, nullptr, x_t, BB, OUT_D, IN_DIM, stream);
    launch_gemm(1, x + IN_DIM, XDIM, me_w1, me_b1, nullptr, x_mh, BB, HID, META_DIM, stream);
    launch_gemm(1, x_mh, HID, me_w2, me_b2, nullptr, x_m, BB, OUT_D, HID, stream);

    // ---- 5. MoE per view (dense experts) ----
    hipMemsetAsync(tmpsum, 0, 16 * sizeof(float), stream);
    const float* xvs[3] = { graph, x_t, x_m };
    for (int v = 0; v < 3; v++) {
        const float* xv = xvs[v];
        moe_gate_kernel<<<BB / 4, 256, 0, stream>>>(
            xv, moe_gate_w + (size_t)v * NEXP * OUT_D, moe_noise_w + (size_t)v * OUT_D,
            noise + (size_t)v * BB * NEXP, comb, tmpsum + v * 4);
        for (int e = 0; e < 4; e++) {
            const float* w1 = moe_w1 + ((size_t)(v * 4 + e)) * FF_D * OUT_D * 0 + ((size_t)(v * 4 + e)) * 512 * 128;
            const float* b1 = moe_b1 + (size_t)(v * 4 + e) * 512;
            const float* w2 = moe_w2 + ((size_t)(v * 4 + e)) * 128 * 512;
            const float* b2 = moe_b2 + (size_t)(v * 4 + e) * 128;
            launch_gemm(1, xv, OUT_D, w1, b1, nullptr, h1buf, BB, 512, OUT_D, stream);
            launch_gemm(0, h1buf, 512, w2, b2, nullptr, eo + (size_t)e * BB * OUT_D, BB, OUT_D, 512, stream);
        }
        moe_combine_kernel<<<(BB * OUT_D) / 256, 256, 0, stream>>>(eo, comb, z + v * OUT_D);
    }

    // ---- 6. transformer x4 on z (8192,3,128) viewed as (24576,128) ----
    const int MT = BB * 3;
    for (int li = 0; li < NLAY; li++) {
        launch_gemm(0, z, 128, tf_qkv_w + (size_t)li * 384 * 128, tf_qkv_b + li * 384,
                    nullptr, qkv, MT, 384, 128, stream);
        attn_kernel<<<(BB * 4) / 8, 256, 0, stream>>>(qkv, attn_o);
        launch_gemm(0, attn_o, 128, tf_out_w + (size_t)li * 128 * 128, tf_out_b + li * 128,
                    nullptr, tmp1, MT, 128, 128, stream);
        ln_residual_kernel<<<MT / 4, 256, 0, stream>>>(z, tmp1, tf_ln1_g + li * 128, tf_ln1_b + li * 128, MT);
        launch_gemm(1, z, 128, tf_ff1_w + (size_t)li * 512 * 128, tf_ff1_b + li * 512,
                    nullptr, ff1, MT, 512, 128, stream);
        launch_gemm(0, ff1, 512, tf_ff2_w + (size_t)li * 128 * 512, tf_ff2_b + li * 128,
                    nullptr, tmp1, MT, 128, 512, stream);
        ln_residual_kernel<<<MT / 4, 256, 0, stream>>>(z, tmp1, tf_ln2_g + li * 128, tf_ln2_b + li * 128, MT);
    }

    // ---- 7. classifier + loss ----
    launch_gemm(0, z, 384, clf_w, clf_b, nullptr, (float*)d_out, BB, 2, 384, stream);
    loss_kernel<<<1, 64, 0, stream>>>(tmpsum, (float*)d_out + BB * 2);
}

// Round 2
// 2667.745 us; speedup vs baseline: 2.1313x; 2.1313x over previous
//
#include <hip/hip_runtime.h>
#include <hip/hip_bf16.h>
#include <math.h>

// Problem constants
#define NN 40000
#define EE 640000
#define BB 8192
#define IN_DIM 768
#define META_DIM 6
#define XDIM 774      // IN+META
#define HID 256
#define OUT_D 128
#define NEXP 4
#define NET_T 3
#define REL_D 200
#define NLAY 4
#define FF_D 512

typedef __attribute__((ext_vector_type(8))) short short8;
typedef __attribute__((ext_vector_type(4))) float f32x4;

__device__ __forceinline__ ushort f2bf(float f) {
    union { float f; unsigned u; } a; a.f = f;
    unsigned u = a.u;
    unsigned r = (u + 0x7FFFu + ((u >> 16) & 1u)) >> 16;  // RNE
    return (ushort)r;
}

// ---------------------------------------------------------------------------
// fp32 tiled GEMM (GNN / encoder path): C = act(A@B^T + bias + res)
// ACT: 0=none, 1=relu, 2=elu
// ---------------------------------------------------------------------------
template<int ACT>
__global__ void gemm_kernel(const float* __restrict__ A, int lda,
                            const float* __restrict__ Bw,
                            const float* __restrict__ bias,
                            const float* __restrict__ res,
                            float* __restrict__ C, int M, int Nn, int K)
{
    __shared__ float As[16][68];
    __shared__ float Bs[16][68];
    int bm = blockIdx.y * 64, bn = blockIdx.x * 64;
    int t = threadIdx.x;
    int tx = t & 15, ty = t >> 4;
    float acc[4][4] = {{0.f}};

    for (int k0 = 0; k0 < K; k0 += 16) {
#pragma unroll
        for (int i = 0; i < 4; i++) {
            int l = t * 4 + i; int mm = l >> 4, kk = l & 15;
            int gm = bm + mm, gk = k0 + kk;
            As[kk][mm] = (gm < M && gk < K) ? A[(size_t)gm * lda + gk] : 0.f;
        }
#pragma unroll
        for (int i = 0; i < 4; i++) {
            int l = t * 4 + i; int nn = l >> 4, kk = l & 15;
            int gn = bn + nn, gk = k0 + kk;
            Bs[kk][nn] = (gn < Nn && gk < K) ? Bw[(size_t)gn * K + gk] : 0.f;
        }
        __syncthreads();
#pragma unroll
        for (int kk = 0; kk < 16; kk++) {
            float4 a4 = *reinterpret_cast<const float4*>(&As[kk][ty * 4]);
            float4 b4 = *reinterpret_cast<const float4*>(&Bs[kk][tx * 4]);
            float a0[4] = {a4.x, a4.y, a4.z, a4.w};
            float b0[4] = {b4.x, b4.y, b4.z, b4.w};
#pragma unroll
            for (int i = 0; i < 4; i++)
#pragma unroll
                for (int j = 0; j < 4; j++)
                    acc[i][j] += a0[i] * b0[j];
        }
        __syncthreads();
    }
#pragma unroll
    for (int i = 0; i < 4; i++) {
        int gm = bm + ty * 4 + i; if (gm >= M) continue;
#pragma unroll
        for (int j = 0; j < 4; j++) {
            int gn = bn + tx * 4 + j; if (gn >= Nn) continue;
            float v = acc[i][j];
            if (bias) v += bias[gn];
            if (res)  v += res[(size_t)gm * Nn + gn];
            if (ACT == 1) v = fmaxf(v, 0.f);
            else if (ACT == 2) v = (v > 0.f) ? v : expm1f(v);
            C[(size_t)gm * Nn + gn] = v;
        }
    }
}

static void launch_gemm(int act, const float* A, int lda, const float* Bw,
                        const float* bias, const float* res, float* C,
                        int M, int Nn, int K, hipStream_t s)
{
    dim3 grid((Nn + 63) / 64, (M + 63) / 64);
    dim3 blk(256);
    if (act == 0)      gemm_kernel<0><<<grid, blk, 0, s>>>(A, lda, Bw, bias, res, C, M, Nn, K);
    else if (act == 1) gemm_kernel<1><<<grid, blk, 0, s>>>(A, lda, Bw, bias, res, C, M, Nn, K);
    else               gemm_kernel<2><<<grid, blk, 0, s>>>(A, lda, Bw, bias, res, C, M, Nn, K);
}

// ---------------------------------------------------------------------------
// bf16 MFMA GEMM: C[M,N] = act(A[M,K] @ B[N,K]^T + bias), batched over z.
// Block 256 thr = 4 waves; block tile 128x64 (wave tile 64x32);
// 16x16x32 bf16 MFMA; fp32 inputs converted during LDS staging.
// Requires M%128==0, N%64==0, K%32==0.
// A_BF16: A is ushort(bf16). OUT_BF16: C written as ushort(bf16).
// ---------------------------------------------------------------------------
template<int ACT, int A_BF16, int OUT_BF16>
__global__ __launch_bounds__(256) void mfma_gemm(
    const void* __restrict__ Ap, size_t strideAz,
    const float* __restrict__ Bw, size_t strideBz,
    const float* __restrict__ bias, size_t strideBiasz,
    void* __restrict__ Cp, size_t strideCz,
    int M, int Nn, int K)
{
    __shared__ __align__(16) ushort As[128 * 40];
    __shared__ __align__(16) ushort Bs[64 * 40];

    int z = blockIdx.z;
    const float*  Af  = (const float*)Ap  + (A_BF16 ? 0 : z * strideAz);
    const ushort* Ab  = (const ushort*)Ap + (A_BF16 ? z * strideAz : 0);
    const float*  Bwz = Bw + z * strideBz;
    const float*  bz  = bias ? bias + z * strideBiasz : nullptr;
    float*  Cf = (float*)Cp  + (OUT_BF16 ? 0 : z * strideCz);
    ushort* Cb = (ushort*)Cp + (OUT_BF16 ? z * strideCz : 0);

    int bn = blockIdx.x * 64;
    int bm = blockIdx.y * 128;
    int t = threadIdx.x;
    int wave = t >> 6, lane = t & 63;
    int wm = wave & 1, wn = wave >> 1;
    int quad = lane >> 4, r = lane & 15;

    f32x4 acc[4][2];
#pragma unroll
    for (int i = 0; i < 4; i++)
#pragma unroll
        for (int j = 0; j < 2; j++) acc[i][j] = (f32x4){0.f, 0.f, 0.f, 0.f};

    for (int k0 = 0; k0 < K; k0 += 32) {
        // ---- stage A tile (128 x 32) ----
        if (A_BF16) {
#pragma unroll
            for (int i = 0; i < 2; i++) {
                int idx = t + i * 256;           // 512 chunks of 8 bf16
                int row = idx >> 2, c8 = idx & 3;
                short8 v = *(const short8*)(Ab + (size_t)(bm + row) * K + k0 + c8 * 8);
                *(short8*)&As[row * 40 + c8 * 8] = v;
            }
        } else {
#pragma unroll
            for (int i = 0; i < 4; i++) {
                int idx = t + i * 256;           // 1024 float4s
                int row = idx >> 3, c4 = idx & 7;
                float4 f = *(const float4*)(Af + (size_t)(bm + row) * K + k0 + c4 * 4);
                ushort4 u; u.x = f2bf(f.x); u.y = f2bf(f.y); u.z = f2bf(f.z); u.w = f2bf(f.w);
                *(ushort4*)&As[row * 40 + c4 * 4] = u;
            }
        }
        // ---- stage B tile (64 x 32) ----
#pragma unroll
        for (int i = 0; i < 2; i++) {
            int idx = t + i * 256;               // 512 float4s
            int row = idx >> 3, c4 = idx & 7;
            float4 f = *(const float4*)(Bwz + (size_t)(bn + row) * K + k0 + c4 * 4);
            ushort4 u; u.x = f2bf(f.x); u.y = f2bf(f.y); u.z = f2bf(f.z); u.w = f2bf(f.w);
            *(ushort4*)&Bs[row * 40 + c4 * 4] = u;
        }
        __syncthreads();

        short8 af[4], bf[2];
#pragma unroll
        for (int i = 0; i < 4; i++)
            af[i] = *(const short8*)&As[(wm * 64 + i * 16 + r) * 40 + quad * 8];
#pragma unroll
        for (int j = 0; j < 2; j++)
            bf[j] = *(const short8*)&Bs[(wn * 32 + j * 16 + r) * 40 + quad * 8];
#pragma unroll
        for (int i = 0; i < 4; i++)
#pragma unroll
            for (int j = 0; j < 2; j++)
                acc[i][j] = __builtin_amdgcn_mfma_f32_16x16x32_bf16(af[i], bf[j], acc[i][j], 0, 0, 0);
        __syncthreads();
    }

    // ---- epilogue ----
    float bcol[2];
#pragma unroll
    for (int j = 0; j < 2; j++)
        bcol[j] = bz ? bz[bn + wn * 32 + j * 16 + r] : 0.f;
#pragma unroll
    for (int i = 0; i < 4; i++) {
#pragma unroll
        for (int j = 0; j < 2; j++) {
            int col = bn + wn * 32 + j * 16 + r;
#pragma unroll
            for (int reg = 0; reg < 4; reg++) {
                int row = bm + wm * 64 + i * 16 + quad * 4 + reg;
                float v = acc[i][j][reg] + bcol[j];
                if (ACT == 1) v = fmaxf(v, 0.f);
                if (OUT_BF16) Cb[(size_t)row * Nn + col] = f2bf(v);
                else          Cf[(size_t)row * Nn + col] = v;
            }
        }
    }
}

template<int ACT, int A_BF16, int OUT_BF16>
static void mfma_launch(const void* A, size_t sAz, const float* Bw, size_t sBz,
                        const float* bias, size_t sbz, void* C, size_t sCz,
                        int M, int Nn, int K, int batch, hipStream_t s)
{
    dim3 grid(Nn / 64, M / 128, batch);
    mfma_gemm<ACT, A_BF16, OUT_BF16><<<grid, 256, 0, s>>>(A, sAz, Bw, sBz, bias, sbz, C, sCz, M, Nn, K);
}

// ---------------------------------------------------------------------------
// GNN helper kernels
// ---------------------------------------------------------------------------
__global__ void sisj_kernel(const float* __restrict__ Wx, const float* __restrict__ a,
                            float* __restrict__ s_i, float* __restrict__ s_j, int n)
{
    int t = threadIdx.x; int w = t >> 6, l = t & 63;
    int m = blockIdx.x * 4 + w; if (m >= n) return;
    const float* r = Wx + (size_t)m * HID;
    float v1 = 0.f, v2 = 0.f;
#pragma unroll
    for (int i = 0; i < 4; i++) {
        float xv = r[l + 64 * i];
        v1 += xv * a[l + 64 * i];
        v2 += xv * a[HID + l + 64 * i];
    }
    for (int off = 32; off; off >>= 1) { v1 += __shfl_down(v1, off); v2 += __shfl_down(v2, off); }
    if (l == 0) { s_i[m] = v1; s_j[m] = v2; }
}

__global__ void rs_kernel(const float* __restrict__ Wr, const float* __restrict__ rel,
                          const float* __restrict__ a3, float* __restrict__ rs)
{
    __shared__ float red[256];
    int tt = blockIdx.x; int j = threadIdx.x;
    const float* relr = rel + tt * REL_D;
    const float* wr = Wr + (size_t)j * REL_D;
    float wsum = 0.f;
    for (int k = 0; k < REL_D; k++) wsum += wr[k] * relr[k];
    red[j] = wsum * a3[j];
    __syncthreads();
    for (int s2 = 128; s2; s2 >>= 1) { if (j < s2) red[j] += red[j + s2]; __syncthreads(); }
    if (j == 0) rs[tt] = red[0];
}

// ---- CSR build (once per launch) ----
__global__ void deg_kernel(const int* __restrict__ dst, int* __restrict__ deg)
{
    int e = blockIdx.x * blockDim.x + threadIdx.x;
    if (e < EE) atomicAdd(&deg[dst[e]], 1);
}

__global__ void scan_kernel(const int* __restrict__ deg, int* __restrict__ rowstart,
                            int* __restrict__ cursor, int n)
{
    __shared__ int buf[1024];
    __shared__ int carry;
    int t = threadIdx.x;
    if (t == 0) carry = 0;
    __syncthreads();
    for (int c = 0; c < n; c += 1024) {
        int v = (c + t < n) ? deg[c + t] : 0;
        buf[t] = v;
        __syncthreads();
        for (int off = 1; off < 1024; off <<= 1) {
            int x = (t >= off) ? buf[t - off] : 0;
            __syncthreads();
            buf[t] += x;
            __syncthreads();
        }
        int incl = buf[t];
        int base = carry;
        if (c + t < n) { rowstart[c + t] = base + incl - v; cursor[c + t] = base + incl - v; }
        __syncthreads();
        if (t == 1023) carry = base + incl;
        __syncthreads();
    }
    if (t == 0) rowstart[n] = carry;
}

__global__ void fill_kernel(const int* __restrict__ src, const int* __restrict__ dst,
                            const int* __restrict__ et, int* __restrict__ cursor,
                            unsigned* __restrict__ csr_val)
{
    int e = blockIdx.x * blockDim.x + threadIdx.x;
    if (e >= EE) return;
    int d = dst[e];
    int pos = atomicAdd(&cursor[d], 1);
    csr_val[pos] = (unsigned)src[e] | ((unsigned)et[e] << 16);
}

// ---- fused attention-softmax aggregation: wave per dst node ----
__global__ void csr_agg_kernel(const unsigned* __restrict__ csr_val,
                               const int* __restrict__ rowstart,
                               const float* __restrict__ s_i, const float* __restrict__ s_j,
                               const float* __restrict__ rsv,
                               const float* __restrict__ Wx, float* __restrict__ agg)
{
    int t = threadIdx.x; int w = t >> 6, l = t & 63;
    int node = blockIdx.x * 4 + w; if (node >= NN) return;
    int start = rowstart[node], end = rowstart[node + 1];
    float r0 = rsv[0], r1 = rsv[1], r2 = rsv[2];
    float si = s_i[node];

    // pass 1: segment max of leaky logits
    float m = -INFINITY;
    for (int i = start + l; i < end; i += 64) {
        unsigned v = csr_val[i];
        int s = v & 0xFFFF; int et = v >> 16;
        float rr = (et == 0) ? r0 : ((et == 1) ? r1 : r2);
        float lg = si + s_j[s] + rr;
        lg = (lg >= 0.f) ? lg : 0.2f * lg;
        m = fmaxf(m, lg);
    }
    for (int off = 32; off; off >>= 1) m = fmaxf(m, __shfl_down(m, off));
    m = __shfl(m, 0);

    // pass 2: accumulate exp weights and weighted Wx rows
    float a0 = 0.f, a1 = 0.f, a2 = 0.f, a3 = 0.f, ssum = 0.f;
    for (int c = start; c < end; c += 64) {
        int nchunk = min(64, end - c);
        float wgt = 0.f; int sidx = 0;
        if (l < nchunk) {
            unsigned v = csr_val[c + l];
            sidx = v & 0xFFFF; int et = v >> 16;
            float rr = (et == 0) ? r0 : ((et == 1) ? r1 : r2);
            float lg = si + s_j[sidx] + rr;
            lg = (lg >= 0.f) ? lg : 0.2f * lg;
            wgt = expf(lg - m);
            ssum += wgt;
        }
        for (int j = 0; j < nchunk; j++) {
            float wj = __shfl(wgt, j);
            int sj = __shfl(sidx, j);
            const float* wr = Wx + (size_t)sj * HID;
            a0 += wj * wr[l];
            a1 += wj * wr[l + 64];
            a2 += wj * wr[l + 128];
            a3 += wj * wr[l + 192];
        }
    }
    for (int off = 32; off; off >>= 1) ssum += __shfl_down(ssum, off);
    ssum = __shfl(ssum, 0);
    float inv = 1.f / (ssum + 1e-16f);
    float* ar = agg + (size_t)node * HID;
    ar[l] = a0 * inv; ar[l + 64] = a1 * inv; ar[l + 128] = a2 * inv; ar[l + 192] = a3 * inv;
}

__global__ void rownorm_kernel(float* __restrict__ h, int n)
{
    int t = threadIdx.x; int w = t >> 6, l = t & 63;
    int m = blockIdx.x * 4 + w; if (m >= n) return;
    float* r = h + (size_t)m * HID;
    float vals[4]; float q = 0.f;
#pragma unroll
    for (int i = 0; i < 4; i++) { vals[i] = r[l + 64 * i]; q += vals[i] * vals[i]; }
    for (int off = 32; off; off >>= 1) q += __shfl_down(q, off);
    q = __shfl(q, 0);
    float inv = 1.f / fmaxf(sqrtf(q), 1e-12f);
#pragma unroll
    for (int i = 0; i < 4; i++) r[l + 64 * i] = vals[i] * inv;
}

// ---------------------------------------------------------------------------
// MoE gating (fp32 end-to-end; feeds the discrete top-k)
// ---------------------------------------------------------------------------
__global__ void moe_gate_kernel(const float* __restrict__ xv, const float* __restrict__ gate_w,
                                const float* __restrict__ noise_w, const float* __restrict__ eps,
                                float* __restrict__ comb, float* __restrict__ tmpsum)
{
    __shared__ float part[4];
    int t = threadIdx.x; int w = t >> 6, l = t & 63;
    if (t < 4) part[t] = 0.f;
    __syncthreads();
    int b = blockIdx.x * 4 + w;
    const float* xr = xv + (size_t)b * OUT_D;
    float x0 = xr[l], x1 = xr[l + 64];
    float dots[5];
#pragma unroll
    for (int e = 0; e < 4; e++) {
        const float* gw = gate_w + e * OUT_D;
        float v = x0 * gw[l] + x1 * gw[l + 64];
        for (int off = 32; off; off >>= 1) v += __shfl_down(v, off);
        dots[e] = v;
    }
    {
        float v = x0 * noise_w[l] + x1 * noise_w[l + 64];
        for (int off = 32; off; off >>= 1) v += __shfl_down(v, off);
        dots[4] = v;
    }
    if (l == 0) {
        float xg = dots[4];
        float nsd = (xg > 20.f) ? xg : log1pf(expf(xg));
        float hv[4];
#pragma unroll
        for (int e = 0; e < 4; e++) hv[e] = dots[e] + eps[(size_t)b * 4 + e] * nsd;
        int i1 = 0;
        for (int e = 1; e < 4; e++) if (hv[e] < hv[i1]) i1 = e;
        int i2 = -1;
        for (int e = 0; e < 4; e++) { if (e == i1) continue; if (i2 < 0 || hv[e] < hv[i2]) i2 = e; }
        int k1 = -1, k2 = -1;
        for (int e = 0; e < 4; e++) { if (e != i1 && e != i2) { if (k1 < 0) k1 = e; else k2 = e; } }
        float mm = fmaxf(hv[k1], hv[k2]);
        float e1 = expf(hv[k1] - mm), e2 = expf(hv[k2] - mm);
        float s = e1 + e2;
        float L[4] = {0.f, 0.f, 0.f, 0.f};
        L[k1] = e1 / s; L[k2] = e2 / s;
#pragma unroll
        for (int e = 0; e < 4; e++) comb[(size_t)b * 4 + e] = L[e];
        atomicAdd(&part[k1], L[k1]);
        atomicAdd(&part[k2], L[k2]);
    }
    __syncthreads();
    if (t < 4) atomicAdd(&tmpsum[t], part[t]);
}

__global__ void moe_combine_kernel(const float* __restrict__ eo, const float* __restrict__ comb,
                                   float* __restrict__ zout)
{
    int idx = blockIdx.x * blockDim.x + threadIdx.x;
    if (idx >= BB * OUT_D) return;
    int b = idx >> 7, o = idx & 127;
    const size_t S = (size_t)BB * OUT_D;
    float v = comb[b * 4 + 0] * eo[idx] + comb[b * 4 + 1] * eo[idx + S]
            + comb[b * 4 + 2] * eo[idx + 2 * S] + comb[b * 4 + 3] * eo[idx + 3 * S];
    zout[(size_t)b * (3 * OUT_D) + o] = v;
}

__global__ void loss_kernel(const float* __restrict__ tmpsum, float* __restrict__ out)
{
    if (threadIdx.x == 0 && blockIdx.x == 0) {
        float total = 0.f;
        for (int v = 0; v < 3; v++) {
            const float* tp = tmpsum + v * 4;
            float mean = (tp[0] + tp[1] + tp[2] + tp[3]) * 0.25f;
            float var = 0.f;
            for (int e = 0; e < 4; e++) { float d = tp[e] - mean; var += d * d; }
            var /= 3.f;
            float r = sqrtf(var) / mean;
            total += r * r;
        }
        out[0] = total;
    }
}

// ---------------------------------------------------------------------------
// Transformer small kernels
// ---------------------------------------------------------------------------
__global__ void attn_kernel(const float* __restrict__ qkv, float* __restrict__ o)
{
    int t = threadIdx.x;
    int half = t >> 5;
    int d = t & 31;
    int task = blockIdx.x * 8 + half;   // b*4 + h
    int b = task >> 2, h = task & 3;
    const float* base = qkv + (size_t)b * 3 * 384 + h * 32;
    float q0 = base[d],       q1 = base[384 + d],       q2 = base[768 + d];
    float k0 = base[128 + d], k1 = base[384 + 128 + d], k2 = base[768 + 128 + d];
    float v0 = base[256 + d], v1 = base[384 + 256 + d], v2 = base[768 + 256 + d];
    float s[3][3];
    s[0][0] = q0 * k0; s[0][1] = q0 * k1; s[0][2] = q0 * k2;
    s[1][0] = q1 * k0; s[1][1] = q1 * k1; s[1][2] = q1 * k2;
    s[2][0] = q2 * k0; s[2][1] = q2 * k1; s[2][2] = q2 * k2;
#pragma unroll
    for (int i = 0; i < 3; i++)
#pragma unroll
        for (int j = 0; j < 3; j++) {
            float v = s[i][j];
            for (int off = 16; off; off >>= 1) v += __shfl_xor(v, off, 32);
            s[i][j] = v;
        }
    const float scale = 0.17677669529663687f;
    float outv[3];
#pragma unroll
    for (int i = 0; i < 3; i++) {
        float a0 = s[i][0] * scale, a1 = s[i][1] * scale, a2 = s[i][2] * scale;
        float m = fmaxf(a0, fmaxf(a1, a2));
        float e0 = expf(a0 - m), e1 = expf(a1 - m), e2 = expf(a2 - m);
        float inv = 1.f / (e0 + e1 + e2);
        outv[i] = (e0 * v0 + e1 * v1 + e2 * v2) * inv;
    }
    float* ob = o + (size_t)b * 3 * 128 + h * 32;
    ob[d] = outv[0]; ob[128 + d] = outv[1]; ob[256 + d] = outv[2];
}

__global__ void ln_residual_kernel(float* __restrict__ x, const float* __restrict__ add,
                                   const float* __restrict__ g, const float* __restrict__ bta, int M)
{
    int t = threadIdx.x; int w = t >> 6, l = t & 63;
    int row = blockIdx.x * 4 + w; if (row >= M) return;
    float* xr = x + (size_t)row * 128;
    const float* ar = add + (size_t)row * 128;
    float v0 = xr[l] + ar[l], v1 = xr[l + 64] + ar[l + 64];
    float s = v0 + v1;
    for (int off = 32; off; off >>= 1) s += __shfl_down(s, off);
    s = __shfl(s, 0);
    float mu = s * (1.f / 128.f);
    float d0 = v0 - mu, d1 = v1 - mu;
    float q = d0 * d0 + d1 * d1;
    for (int off = 32; off; off >>= 1) q += __shfl_down(q, off);
    q = __shfl(q, 0);
    float inv = rsqrtf(q * (1.f / 128.f) + 1e-5f);
    xr[l]      = d0 * inv * g[l] + bta[l];
    xr[l + 64] = d1 * inv * g[l + 64] + bta[l + 64];
}

__global__ void clf_kernel(const float* __restrict__ z, const float* __restrict__ w,
                           const float* __restrict__ b, float* __restrict__ out)
{
    int t = threadIdx.x; int wv = t >> 6, l = t & 63;
    int row = blockIdx.x * 4 + wv; if (row >= BB) return;
    const float* zr = z + (size_t)row * 384;
    float v0 = 0.f, v1 = 0.f;
    for (int i = l; i < 384; i += 64) {
        float zz = zr[i];
        v0 += zz * w[i];
        v1 += zz * w[384 + i];
    }
    for (int off = 32; off; off >>= 1) { v0 += __shfl_down(v0, off); v1 += __shfl_down(v1, off); }
    if (l == 0) { out[row * 2] = v0 + b[0]; out[row * 2 + 1] = v1 + b[1]; }
}

// ---------------------------------------------------------------------------
// Orchestration
// ---------------------------------------------------------------------------
extern "C" void kernel_launch(void* const* d_in, const int* in_sizes, int n_in,
                              void* d_out, int out_size, void* d_ws, size_t ws_size,
                              hipStream_t stream)
{
    const float* x         = (const float*)d_in[0];
    const float* noise     = (const float*)d_in[1];
    const float* g_lin1_w  = (const float*)d_in[2];
    const float* g_lin1_b  = (const float*)d_in[3];
    const float* conv_W    = (const float*)d_in[4];
    const float* conv_Wr   = (const float*)d_in[5];
    const float* conv_a    = (const float*)d_in[6];
    const float* conv_Wres = (const float*)d_in[7];
    const float* conv_rel  = (const float*)d_in[8];
    const float* g_lin2_w  = (const float*)d_in[9];
    const float* g_lin2_b  = (const float*)d_in[10];
    const float* te_w      = (const float*)d_in[11];
    const float* te_b      = (const float*)d_in[12];
    const float* me_w1     = (const float*)d_in[13];
    const float* me_b1     = (const float*)d_in[14];
    const float* me_w2     = (const float*)d_in[15];
    const float* me_b2     = (const float*)d_in[16];
    const float* moe_gate_w  = (const float*)d_in[17];
    const float* moe_noise_w = (const float*)d_in[18];
    const float* moe_w1    = (const float*)d_in[19];
    const float* moe_b1    = (const float*)d_in[20];
    const float* moe_w2    = (const float*)d_in[21];
    const float* moe_b2    = (const float*)d_in[22];
    const float* tf_qkv_w  = (const float*)d_in[23];
    const float* tf_qkv_b  = (const float*)d_in[24];
    const float* tf_out_w  = (const float*)d_in[25];
    const float* tf_out_b  = (const float*)d_in[26];
    const float* tf_ln1_g  = (const float*)d_in[27];
    const float* tf_ln1_b  = (const float*)d_in[28];
    const float* tf_ff1_w  = (const float*)d_in[29];
    const float* tf_ff1_b  = (const float*)d_in[30];
    const float* tf_ff2_w  = (const float*)d_in[31];
    const float* tf_ff2_b  = (const float*)d_in[32];
    const float* tf_ln2_g  = (const float*)d_in[33];
    const float* tf_ln2_b  = (const float*)d_in[34];
    const float* clf_w     = (const float*)d_in[35];
    const float* clf_b     = (const float*)d_in[36];
    const int*   edge_index = (const int*)d_in[37];
    const int*   edge_type  = (const int*)d_in[38];

    float* ws = (float*)d_ws;

    // Arena (floats):
    //  A @ 0          (10.24M): h0 / h2 / qkv
    //  B @ 10,240,000 (12.58M): wx / graph / ff1(bf16)
    //  C @ 22,822,912 (10.24M): agg / x_mh / h1buf(bf16) / attn_o+tmp1
    //  D @ 33,062,912 (10.24M): hl1 / [z, x_t, x_m, eo]
    //  M @ 43,302,912 : misc + CSR
    const size_t F_A = 0;
    const size_t F_B = 10240000;
    const size_t F_C = 22822912;
    const size_t F_D = 33062912;
    const size_t F_M = 43302912;

    float* h0     = ws + F_A;
    float* qkv    = ws + F_A;
    float* wx     = ws + F_B;
    float* graph  = ws + F_B;
    ushort* ff1bf = (ushort*)(ws + F_B);
    float* agg    = ws + F_C;
    float* x_mh   = ws + F_C;
    ushort* h1bf  = (ushort*)(ws + F_C);
    float* attn_o = ws + F_C;
    float* tmp1   = ws + F_C + 3200000;
    float* hl1    = ws + F_D;
    float* z      = ws + F_D;
    float* x_t    = ws + F_D + 3200000;
    float* x_m    = ws + F_D + 4300000;
    float* eo     = ws + F_D + 5400000;

    float* s_i    = ws + F_M;
    float* s_j    = ws + F_M + 40000;
    float* rsv    = ws + F_M + 80000;
    float* comb   = ws + F_M + 80016;
    float* tmpsum = ws + F_M + 112784;
    int* deg      = (int*)(ws + F_M + 120000);
    int* rowstart = (int*)(ws + F_M + 161000);
    int* cursor   = (int*)(ws + F_M + 202000);
    unsigned* csr_val = (unsigned*)(ws + F_M + 242000);

    const int* srcv = edge_index;
    const int* dstv = edge_index + EE;

    // ---- 0. CSR build (edge structure is launch-invariant within a call) ----
    hipMemsetAsync(deg, 0, NN * sizeof(int), stream);
    deg_kernel<<<(EE + 255) / 256, 256, 0, stream>>>(dstv, deg);
    scan_kernel<<<1, 1024, 0, stream>>>(deg, rowstart, cursor, NN);
    fill_kernel<<<(EE + 255) / 256, 256, 0, stream>>>(srcv, dstv, edge_type, cursor, csr_val);

    // ---- 1. h = relu(x @ g_lin1_w.T + b) ----
    launch_gemm(1, x, XDIM, g_lin1_w, g_lin1_b, nullptr, h0, NN, HID, XDIM, stream);

    // ---- 2. two HGN layers ----
    float* hin = h0;
    float* hout = hl1;
    for (int layer = 0; layer < 2; layer++) {
        const float* W    = conv_W    + (size_t)layer * HID * HID;
        const float* Wr   = conv_Wr   + (size_t)layer * HID * REL_D;
        const float* a    = conv_a    + (size_t)layer * 3 * HID;
        const float* Wres = conv_Wres + (size_t)layer * HID * HID;
        const float* rel  = conv_rel  + (size_t)layer * NET_T * REL_D;

        launch_gemm(0, hin, HID, W, nullptr, nullptr, wx, NN, HID, HID, stream);
        sisj_kernel<<<NN / 4, 256, 0, stream>>>(wx, a, s_i, s_j, NN);
        rs_kernel<<<NET_T, 256, 0, stream>>>(Wr, rel, a + 2 * HID, rsv);
        csr_agg_kernel<<<NN / 4, 256, 0, stream>>>(csr_val, rowstart, s_i, s_j, rsv, wx, agg);
        launch_gemm(2, hin, HID, Wres, nullptr, agg, hout, NN, HID, HID, stream);
        if (layer == 1) rownorm_kernel<<<NN / 4, 256, 0, stream>>>(hout, NN);
        float* t2 = hin; hin = hout; hout = t2;
    }
    float* h2 = hin;  // in region A

    // ---- 3. graph = relu(h2 @ g_lin2.T + b) ----
    launch_gemm(1, h2, HID, g_lin2_w, g_lin2_b, nullptr, graph, NN, OUT_D, HID, stream);

    // ---- 4. view encoders (fp32: feed the discrete gate) ----
    launch_gemm(1, x, XDIM, te_w, te_b, nullptr, x_t, BB, OUT_D, IN_DIM, stream);
    launch_gemm(1, x + IN_DIM, XDIM, me_w1, me_b1, nullptr, x_mh, BB, HID, META_DIM, stream);
    launch_gemm(1, x_mh, HID, me_w2, me_b2, nullptr, x_m, BB, OUT_D, HID, stream);

    // ---- 5. MoE per view: fp32 gate, bf16 MFMA experts ----
    hipMemsetAsync(tmpsum, 0, 16 * sizeof(float), stream);
    const float* xvs[3] = { graph, x_t, x_m };
    for (int v = 0; v < 3; v++) {
        const float* xv = xvs[v];
        moe_gate_kernel<<<BB / 4, 256, 0, stream>>>(
            xv, moe_gate_w + (size_t)v * NEXP * OUT_D, moe_noise_w + (size_t)v * OUT_D,
            noise + (size_t)v * BB * NEXP, comb, tmpsum + v * 4);
        // h1[e] = relu(xv @ w1[e]^T + b1[e])  -> bf16, all 4 experts batched
        mfma_launch<1, 0, 1>(xv, 0,
                             moe_w1 + (size_t)v * 4 * FF_D * OUT_D, (size_t)FF_D * OUT_D,
                             moe_b1 + (size_t)v * 4 * FF_D, FF_D,
                             h1bf, (size_t)BB * FF_D,
                             BB, FF_D, OUT_D, 4, stream);
        // eo[e] = h1[e] @ w2[e]^T + b2[e]  (A bf16 -> fp32 out)
        mfma_launch<0, 1, 0>(h1bf, (size_t)BB * FF_D,
                             moe_w2 + (size_t)v * 4 * OUT_D * FF_D, (size_t)OUT_D * FF_D,
                             moe_b2 + (size_t)v * 4 * OUT_D, OUT_D,
                             eo, (size_t)BB * OUT_D,
                             BB, OUT_D, FF_D, 4, stream);
        moe_combine_kernel<<<(BB * OUT_D) / 256, 256, 0, stream>>>(eo, comb, z + v * OUT_D);
    }

    // ---- 6. transformer x4 on z (24576,128) ----
    const int MT = BB * 3;
    for (int li = 0; li < NLAY; li++) {
        mfma_launch<0, 0, 0>(z, 0, tf_qkv_w + (size_t)li * 384 * 128, 0,
                             tf_qkv_b + li * 384, 0, qkv, 0, MT, 384, 128, 1, stream);
        attn_kernel<<<(BB * 4) / 8, 256, 0, stream>>>(qkv, attn_o);
        mfma_launch<0, 0, 0>(attn_o, 0, tf_out_w + (size_t)li * 128 * 128, 0,
                             tf_out_b + li * 128, 0, tmp1, 0, MT, 128, 128, 1, stream);
        ln_residual_kernel<<<MT / 4, 256, 0, stream>>>(z, tmp1, tf_ln1_g + li * 128, tf_ln1_b + li * 128, MT);
        mfma_launch<1, 0, 1>(z, 0, tf_ff1_w + (size_t)li * 512 * 128, 0,
                             tf_ff1_b + li * 512, 0, ff1bf, 0, MT, 512, 128, 1, stream);
        mfma_launch<0, 1, 0>(ff1bf, 0, tf_ff2_w + (size_t)li * 128 * 512, 0,
                             tf_ff2_b + li * 128, 0, tmp1, 0, MT, 128, 512, 1, stream);
        ln_residual_kernel<<<MT / 4, 256, 0, stream>>>(z, tmp1, tf_ln2_g + li * 128, tf_ln2_b + li * 128, MT);
    }

    // ---- 7. classifier + loss ----
    clf_kernel<<<BB / 4, 256, 0, stream>>>(z, clf_w, clf_b, (float*)d_out);
    loss_kernel<<<1, 64, 0, stream>>>(tmpsum, (float*)d_out + BB * 2);
}

// Round 3
// 1875.366 us; speedup vs baseline: 3.0318x; 1.4225x over previous
//
#include <hip/hip_runtime.h>
#include <hip/hip_bf16.h>
#include <math.h>

// Problem constants
#define NN 40000
#define EE 640000
#define BB 8192
#define IN_DIM 768
#define META_DIM 6
#define XDIM 774      // IN+META
#define HID 256
#define OUT_D 128
#define NEXP 4
#define NET_T 3
#define REL_D 200
#define NLAY 4
#define FF_D 512

typedef __attribute__((ext_vector_type(8))) short short8;
typedef __attribute__((ext_vector_type(4))) float f32x4;

__device__ __forceinline__ ushort f2bf(float f) {
    union { float f; unsigned u; } a; a.f = f;
    unsigned u = a.u;
    unsigned r = (u + 0x7FFFu + ((u >> 16) & 1u)) >> 16;  // RNE
    return (ushort)r;
}
__device__ __forceinline__ float bf2f(ushort h) {
    union { unsigned u; float f; } a; a.u = ((unsigned)h) << 16;
    return a.f;
}

// ---------------------------------------------------------------------------
// fp32 -> (hi,lo) bf16 split with K padding. src is R x Kreal (lda=ldsrc),
// dst are R x ldp, zero-filled beyond Kreal.
// ---------------------------------------------------------------------------
__global__ void cvt_kernel(const float* __restrict__ src, int ldsrc, int Kreal,
                           ushort* __restrict__ hi, ushort* __restrict__ lo,
                           int R, int ldp)
{
    size_t i = (size_t)blockIdx.x * blockDim.x + threadIdx.x;
    size_t total = (size_t)R * ldp;
    if (i >= total) return;
    int col = (int)(i % ldp);
    int row = (int)(i / ldp);
    float v = (col < Kreal) ? src[(size_t)row * ldsrc + col] : 0.f;
    ushort h = f2bf(v);
    float rem = v - bf2f(h);
    hi[i] = h;
    lo[i] = f2bf(rem);
}

static void cvt(const float* src, int ldsrc, int Kreal, ushort* hi, ushort* lo,
                int R, int ldp, hipStream_t s)
{
    size_t total = (size_t)R * ldp;
    cvt_kernel<<<(int)((total + 255) / 256), 256, 0, s>>>(src, ldsrc, Kreal, hi, lo, R, ldp);
}

// ---------------------------------------------------------------------------
// Split-bf16 (3xMFMA) fp32-precision GEMM:
//   C[M,N] = act(Ahi/lo[M,K] @ (Bhi/lo[N,K])^T + bias + res)
// acc = Ah*Bh + Ah*Bl + Al*Bh  (fp32 accumulate) -> ~fp32 accuracy.
// Block 256 thr, tile 128x64, K-step 32. Requires N%64==0, K%32==0 (padded).
// M arbitrary (row-clamped loads, guarded stores).
// ACT: 0=none, 1=relu, 2=elu. HAS_RES: add res[M,N] before activation.
// ---------------------------------------------------------------------------
template<int ACT, int HAS_RES>
__global__ __launch_bounds__(256) void mfma_gemm3(
    const ushort* __restrict__ Ahi, const ushort* __restrict__ Alo, int lda,
    const ushort* __restrict__ Bhi, const ushort* __restrict__ Blo, int ldb,
    const float* __restrict__ bias, const float* __restrict__ res,
    float* __restrict__ C, int M, int Nn, int K)
{
    __shared__ __align__(16) ushort Ash[128 * 40];
    __shared__ __align__(16) ushort Asl[128 * 40];
    __shared__ __align__(16) ushort Bsh[64 * 40];
    __shared__ __align__(16) ushort Bsl[64 * 40];

    int bn = blockIdx.x * 64;
    int bm = blockIdx.y * 128;
    int t = threadIdx.x;
    int wave = t >> 6, lane = t & 63;
    int wm = wave & 1, wn = wave >> 1;
    int quad = lane >> 4, r = lane & 15;

    f32x4 acc[4][2];
#pragma unroll
    for (int i = 0; i < 4; i++)
#pragma unroll
        for (int j = 0; j < 2; j++) acc[i][j] = (f32x4){0.f, 0.f, 0.f, 0.f};

    for (int k0 = 0; k0 < K; k0 += 32) {
#pragma unroll
        for (int i = 0; i < 2; i++) {
            int idx = t + i * 256;               // 512 short8 chunks (128x32)
            int row = idx >> 2, c8 = idx & 3;
            int grow = bm + row; if (grow > M - 1) grow = M - 1;
            size_t off = (size_t)grow * lda + k0 + c8 * 8;
            *(short8*)&Ash[row * 40 + c8 * 8] = *(const short8*)(Ahi + off);
            *(short8*)&Asl[row * 40 + c8 * 8] = *(const short8*)(Alo + off);
        }
        {
            int row = t >> 2, c8 = t & 3;        // 256 short8 chunks (64x32)
            size_t off = (size_t)(bn + row) * ldb + k0 + c8 * 8;
            *(short8*)&Bsh[row * 40 + c8 * 8] = *(const short8*)(Bhi + off);
            *(short8*)&Bsl[row * 40 + c8 * 8] = *(const short8*)(Blo + off);
        }
        __syncthreads();

        short8 ah[4], al[4], bh[2], bl[2];
#pragma unroll
        for (int i = 0; i < 4; i++) {
            int ro = (wm * 64 + i * 16 + r) * 40 + quad * 8;
            ah[i] = *(const short8*)&Ash[ro];
            al[i] = *(const short8*)&Asl[ro];
        }
#pragma unroll
        for (int j = 0; j < 2; j++) {
            int ro = (wn * 32 + j * 16 + r) * 40 + quad * 8;
            bh[j] = *(const short8*)&Bsh[ro];
            bl[j] = *(const short8*)&Bsl[ro];
        }
#pragma unroll
        for (int i = 0; i < 4; i++)
#pragma unroll
            for (int j = 0; j < 2; j++)
                acc[i][j] = __builtin_amdgcn_mfma_f32_16x16x32_bf16(ah[i], bh[j], acc[i][j], 0, 0, 0);
#pragma unroll
        for (int i = 0; i < 4; i++)
#pragma unroll
            for (int j = 0; j < 2; j++)
                acc[i][j] = __builtin_amdgcn_mfma_f32_16x16x32_bf16(ah[i], bl[j], acc[i][j], 0, 0, 0);
#pragma unroll
        for (int i = 0; i < 4; i++)
#pragma unroll
            for (int j = 0; j < 2; j++)
                acc[i][j] = __builtin_amdgcn_mfma_f32_16x16x32_bf16(al[i], bh[j], acc[i][j], 0, 0, 0);
        __syncthreads();
    }

    float bcol[2];
#pragma unroll
    for (int j = 0; j < 2; j++)
        bcol[j] = bias ? bias[bn + wn * 32 + j * 16 + r] : 0.f;
#pragma unroll
    for (int i = 0; i < 4; i++) {
#pragma unroll
        for (int j = 0; j < 2; j++) {
            int col = bn + wn * 32 + j * 16 + r;
#pragma unroll
            for (int reg = 0; reg < 4; reg++) {
                int row = bm + wm * 64 + i * 16 + quad * 4 + reg;
                if (row >= M) continue;
                float v = acc[i][j][reg] + bcol[j];
                if (HAS_RES) v += res[(size_t)row * Nn + col];
                if (ACT == 1) v = fmaxf(v, 0.f);
                else if (ACT == 2) v = (v > 0.f) ? v : expm1f(v);
                C[(size_t)row * Nn + col] = v;
            }
        }
    }
}

template<int ACT, int HAS_RES>
static void mfma3_launch(const ushort* Ahi, const ushort* Alo, int lda,
                         const ushort* Bhi, const ushort* Blo, int ldb,
                         const float* bias, const float* res, float* C,
                         int M, int Nn, int K, hipStream_t s)
{
    dim3 grid(Nn / 64, (M + 127) / 128);
    mfma_gemm3<ACT, HAS_RES><<<grid, 256, 0, s>>>(Ahi, Alo, lda, Bhi, Blo, ldb,
                                                  bias, res, C, M, Nn, K);
}

// ---------------------------------------------------------------------------
// fp32 tiled GEMM (small leftovers: me chain)
// ---------------------------------------------------------------------------
template<int ACT>
__global__ void gemm_kernel(const float* __restrict__ A, int lda,
                            const float* __restrict__ Bw,
                            const float* __restrict__ bias,
                            const float* __restrict__ res,
                            float* __restrict__ C, int M, int Nn, int K)
{
    __shared__ float As[16][68];
    __shared__ float Bs[16][68];
    int bm = blockIdx.y * 64, bn = blockIdx.x * 64;
    int t = threadIdx.x;
    int tx = t & 15, ty = t >> 4;
    float acc[4][4] = {{0.f}};

    for (int k0 = 0; k0 < K; k0 += 16) {
#pragma unroll
        for (int i = 0; i < 4; i++) {
            int l = t * 4 + i; int mm = l >> 4, kk = l & 15;
            int gm = bm + mm, gk = k0 + kk;
            As[kk][mm] = (gm < M && gk < K) ? A[(size_t)gm * lda + gk] : 0.f;
        }
#pragma unroll
        for (int i = 0; i < 4; i++) {
            int l = t * 4 + i; int nn = l >> 4, kk = l & 15;
            int gn = bn + nn, gk = k0 + kk;
            Bs[kk][nn] = (gn < Nn && gk < K) ? Bw[(size_t)gn * K + gk] : 0.f;
        }
        __syncthreads();
#pragma unroll
        for (int kk = 0; kk < 16; kk++) {
            float4 a4 = *reinterpret_cast<const float4*>(&As[kk][ty * 4]);
            float4 b4 = *reinterpret_cast<const float4*>(&Bs[kk][tx * 4]);
            float a0[4] = {a4.x, a4.y, a4.z, a4.w};
            float b0[4] = {b4.x, b4.y, b4.z, b4.w};
#pragma unroll
            for (int i = 0; i < 4; i++)
#pragma unroll
                for (int j = 0; j < 4; j++)
                    acc[i][j] += a0[i] * b0[j];
        }
        __syncthreads();
    }
#pragma unroll
    for (int i = 0; i < 4; i++) {
        int gm = bm + ty * 4 + i; if (gm >= M) continue;
#pragma unroll
        for (int j = 0; j < 4; j++) {
            int gn = bn + tx * 4 + j; if (gn >= Nn) continue;
            float v = acc[i][j];
            if (bias) v += bias[gn];
            if (res)  v += res[(size_t)gm * Nn + gn];
            if (ACT == 1) v = fmaxf(v, 0.f);
            else if (ACT == 2) v = (v > 0.f) ? v : expm1f(v);
            C[(size_t)gm * Nn + gn] = v;
        }
    }
}

static void launch_gemm(int act, const float* A, int lda, const float* Bw,
                        const float* bias, const float* res, float* C,
                        int M, int Nn, int K, hipStream_t s)
{
    dim3 grid((Nn + 63) / 64, (M + 63) / 64);
    dim3 blk(256);
    if (act == 0)      gemm_kernel<0><<<grid, blk, 0, s>>>(A, lda, Bw, bias, res, C, M, Nn, K);
    else if (act == 1) gemm_kernel<1><<<grid, blk, 0, s>>>(A, lda, Bw, bias, res, C, M, Nn, K);
    else               gemm_kernel<2><<<grid, blk, 0, s>>>(A, lda, Bw, bias, res, C, M, Nn, K);
}

// ---------------------------------------------------------------------------
// bf16 MFMA GEMM (downstream-of-gate path): C = act(A@B^T + bias), batched.
// ---------------------------------------------------------------------------
template<int ACT, int A_BF16, int OUT_BF16>
__global__ __launch_bounds__(256) void mfma_gemm(
    const void* __restrict__ Ap, size_t strideAz,
    const float* __restrict__ Bw, size_t strideBz,
    const float* __restrict__ bias, size_t strideBiasz,
    void* __restrict__ Cp, size_t strideCz,
    int M, int Nn, int K)
{
    __shared__ __align__(16) ushort As[128 * 40];
    __shared__ __align__(16) ushort Bs[64 * 40];

    int z = blockIdx.z;
    const float*  Af  = (const float*)Ap  + (A_BF16 ? 0 : z * strideAz);
    const ushort* Ab  = (const ushort*)Ap + (A_BF16 ? z * strideAz : 0);
    const float*  Bwz = Bw + z * strideBz;
    const float*  bz  = bias ? bias + z * strideBiasz : nullptr;
    float*  Cf = (float*)Cp  + (OUT_BF16 ? 0 : z * strideCz);
    ushort* Cb = (ushort*)Cp + (OUT_BF16 ? z * strideCz : 0);

    int bn = blockIdx.x * 64;
    int bm = blockIdx.y * 128;
    int t = threadIdx.x;
    int wave = t >> 6, lane = t & 63;
    int wm = wave & 1, wn = wave >> 1;
    int quad = lane >> 4, r = lane & 15;

    f32x4 acc[4][2];
#pragma unroll
    for (int i = 0; i < 4; i++)
#pragma unroll
        for (int j = 0; j < 2; j++) acc[i][j] = (f32x4){0.f, 0.f, 0.f, 0.f};

    for (int k0 = 0; k0 < K; k0 += 32) {
        if (A_BF16) {
#pragma unroll
            for (int i = 0; i < 2; i++) {
                int idx = t + i * 256;
                int row = idx >> 2, c8 = idx & 3;
                short8 v = *(const short8*)(Ab + (size_t)(bm + row) * K + k0 + c8 * 8);
                *(short8*)&As[row * 40 + c8 * 8] = v;
            }
        } else {
#pragma unroll
            for (int i = 0; i < 4; i++) {
                int idx = t + i * 256;
                int row = idx >> 3, c4 = idx & 7;
                float4 f = *(const float4*)(Af + (size_t)(bm + row) * K + k0 + c4 * 4);
                ushort4 u; u.x = f2bf(f.x); u.y = f2bf(f.y); u.z = f2bf(f.z); u.w = f2bf(f.w);
                *(ushort4*)&As[row * 40 + c4 * 4] = u;
            }
        }
#pragma unroll
        for (int i = 0; i < 2; i++) {
            int idx = t + i * 256;
            int row = idx >> 3, c4 = idx & 7;
            float4 f = *(const float4*)(Bwz + (size_t)(bn + row) * K + k0 + c4 * 4);
            ushort4 u; u.x = f2bf(f.x); u.y = f2bf(f.y); u.z = f2bf(f.z); u.w = f2bf(f.w);
            *(ushort4*)&Bs[row * 40 + c4 * 4] = u;
        }
        __syncthreads();

        short8 af[4], bf[2];
#pragma unroll
        for (int i = 0; i < 4; i++)
            af[i] = *(const short8*)&As[(wm * 64 + i * 16 + r) * 40 + quad * 8];
#pragma unroll
        for (int j = 0; j < 2; j++)
            bf[j] = *(const short8*)&Bs[(wn * 32 + j * 16 + r) * 40 + quad * 8];
#pragma unroll
        for (int i = 0; i < 4; i++)
#pragma unroll
            for (int j = 0; j < 2; j++)
                acc[i][j] = __builtin_amdgcn_mfma_f32_16x16x32_bf16(af[i], bf[j], acc[i][j], 0, 0, 0);
        __syncthreads();
    }

    float bcol[2];
#pragma unroll
    for (int j = 0; j < 2; j++)
        bcol[j] = bz ? bz[bn + wn * 32 + j * 16 + r] : 0.f;
#pragma unroll
    for (int i = 0; i < 4; i++) {
#pragma unroll
        for (int j = 0; j < 2; j++) {
            int col = bn + wn * 32 + j * 16 + r;
#pragma unroll
            for (int reg = 0; reg < 4; reg++) {
                int row = bm + wm * 64 + i * 16 + quad * 4 + reg;
                float v = acc[i][j][reg] + bcol[j];
                if (ACT == 1) v = fmaxf(v, 0.f);
                if (OUT_BF16) Cb[(size_t)row * Nn + col] = f2bf(v);
                else          Cf[(size_t)row * Nn + col] = v;
            }
        }
    }
}

template<int ACT, int A_BF16, int OUT_BF16>
static void mfma_launch(const void* A, size_t sAz, const float* Bw, size_t sBz,
                        const float* bias, size_t sbz, void* C, size_t sCz,
                        int M, int Nn, int K, int batch, hipStream_t s)
{
    dim3 grid(Nn / 64, M / 128, batch);
    mfma_gemm<ACT, A_BF16, OUT_BF16><<<grid, 256, 0, s>>>(A, sAz, Bw, sBz, bias, sbz, C, sCz, M, Nn, K);
}

// ---------------------------------------------------------------------------
// GNN helper kernels
// ---------------------------------------------------------------------------
__global__ void sisj_kernel(const float* __restrict__ Wx, const float* __restrict__ a,
                            float* __restrict__ s_i, float* __restrict__ s_j, int n)
{
    int t = threadIdx.x; int w = t >> 6, l = t & 63;
    int m = blockIdx.x * 4 + w; if (m >= n) return;
    const float* r = Wx + (size_t)m * HID;
    float v1 = 0.f, v2 = 0.f;
#pragma unroll
    for (int i = 0; i < 4; i++) {
        float xv = r[l + 64 * i];
        v1 += xv * a[l + 64 * i];
        v2 += xv * a[HID + l + 64 * i];
    }
    for (int off = 32; off; off >>= 1) { v1 += __shfl_down(v1, off); v2 += __shfl_down(v2, off); }
    if (l == 0) { s_i[m] = v1; s_j[m] = v2; }
}

__global__ void rs_kernel(const float* __restrict__ Wr, const float* __restrict__ rel,
                          const float* __restrict__ a3, float* __restrict__ rs)
{
    __shared__ float red[256];
    int tt = blockIdx.x; int j = threadIdx.x;
    const float* relr = rel + tt * REL_D;
    const float* wr = Wr + (size_t)j * REL_D;
    float wsum = 0.f;
    for (int k = 0; k < REL_D; k++) wsum += wr[k] * relr[k];
    red[j] = wsum * a3[j];
    __syncthreads();
    for (int s2 = 128; s2; s2 >>= 1) { if (j < s2) red[j] += red[j + s2]; __syncthreads(); }
    if (j == 0) rs[tt] = red[0];
}

// ---- CSR build ----
__global__ void deg_kernel(const int* __restrict__ dst, int* __restrict__ deg)
{
    int e = blockIdx.x * blockDim.x + threadIdx.x;
    if (e < EE) atomicAdd(&deg[dst[e]], 1);
}

__global__ void scan_kernel(const int* __restrict__ deg, int* __restrict__ rowstart,
                            int* __restrict__ cursor, int n)
{
    __shared__ int buf[1024];
    __shared__ int carry;
    int t = threadIdx.x;
    if (t == 0) carry = 0;
    __syncthreads();
    for (int c = 0; c < n; c += 1024) {
        int v = (c + t < n) ? deg[c + t] : 0;
        buf[t] = v;
        __syncthreads();
        for (int off = 1; off < 1024; off <<= 1) {
            int x = (t >= off) ? buf[t - off] : 0;
            __syncthreads();
            buf[t] += x;
            __syncthreads();
        }
        int incl = buf[t];
        int base = carry;
        if (c + t < n) { rowstart[c + t] = base + incl - v; cursor[c + t] = base + incl - v; }
        __syncthreads();
        if (t == 1023) carry = base + incl;
        __syncthreads();
    }
    if (t == 0) rowstart[n] = carry;
}

__global__ void fill_kernel(const int* __restrict__ src, const int* __restrict__ dst,
                            const int* __restrict__ et, int* __restrict__ cursor,
                            unsigned* __restrict__ csr_val)
{
    int e = blockIdx.x * blockDim.x + threadIdx.x;
    if (e >= EE) return;
    int d = dst[e];
    int pos = atomicAdd(&cursor[d], 1);
    csr_val[pos] = (unsigned)src[e] | ((unsigned)et[e] << 16);
}

// ---- fused attention-softmax aggregation: wave per dst node ----
__global__ void csr_agg_kernel(const unsigned* __restrict__ csr_val,
                               const int* __restrict__ rowstart,
                               const float* __restrict__ s_i, const float* __restrict__ s_j,
                               const float* __restrict__ rsv,
                               const float* __restrict__ Wx, float* __restrict__ agg)
{
    int t = threadIdx.x; int w = t >> 6, l = t & 63;
    int node = blockIdx.x * 4 + w; if (node >= NN) return;
    int start = rowstart[node], end = rowstart[node + 1];
    float r0 = rsv[0], r1 = rsv[1], r2 = rsv[2];
    float si = s_i[node];

    float m = -INFINITY;
    for (int i = start + l; i < end; i += 64) {
        unsigned v = csr_val[i];
        int s = v & 0xFFFF; int et = v >> 16;
        float rr = (et == 0) ? r0 : ((et == 1) ? r1 : r2);
        float lg = si + s_j[s] + rr;
        lg = (lg >= 0.f) ? lg : 0.2f * lg;
        m = fmaxf(m, lg);
    }
    for (int off = 32; off; off >>= 1) m = fmaxf(m, __shfl_down(m, off));
    m = __shfl(m, 0);

    float a0 = 0.f, a1 = 0.f, a2 = 0.f, a3 = 0.f, ssum = 0.f;
    for (int c = start; c < end; c += 64) {
        int nchunk = min(64, end - c);
        float wgt = 0.f; int sidx = 0;
        if (l < nchunk) {
            unsigned v = csr_val[c + l];
            sidx = v & 0xFFFF; int et = v >> 16;
            float rr = (et == 0) ? r0 : ((et == 1) ? r1 : r2);
            float lg = si + s_j[sidx] + rr;
            lg = (lg >= 0.f) ? lg : 0.2f * lg;
            wgt = expf(lg - m);
            ssum += wgt;
        }
        for (int j = 0; j < nchunk; j++) {
            float wj = __shfl(wgt, j);
            int sj = __shfl(sidx, j);
            const float* wr = Wx + (size_t)sj * HID;
            a0 += wj * wr[l];
            a1 += wj * wr[l + 64];
            a2 += wj * wr[l + 128];
            a3 += wj * wr[l + 192];
        }
    }
    for (int off = 32; off; off >>= 1) ssum += __shfl_down(ssum, off);
    ssum = __shfl(ssum, 0);
    float inv = 1.f / (ssum + 1e-16f);
    float* ar = agg + (size_t)node * HID;
    ar[l] = a0 * inv; ar[l + 64] = a1 * inv; ar[l + 128] = a2 * inv; ar[l + 192] = a3 * inv;
}

__global__ void rownorm_kernel(float* __restrict__ h, int n)
{
    int t = threadIdx.x; int w = t >> 6, l = t & 63;
    int m = blockIdx.x * 4 + w; if (m >= n) return;
    float* r = h + (size_t)m * HID;
    float vals[4]; float q = 0.f;
#pragma unroll
    for (int i = 0; i < 4; i++) { vals[i] = r[l + 64 * i]; q += vals[i] * vals[i]; }
    for (int off = 32; off; off >>= 1) q += __shfl_down(q, off);
    q = __shfl(q, 0);
    float inv = 1.f / fmaxf(sqrtf(q), 1e-12f);
#pragma unroll
    for (int i = 0; i < 4; i++) r[l + 64 * i] = vals[i] * inv;
}

// ---------------------------------------------------------------------------
// MoE gating (fp32)
// ---------------------------------------------------------------------------
__global__ void moe_gate_kernel(const float* __restrict__ xv, const float* __restrict__ gate_w,
                                const float* __restrict__ noise_w, const float* __restrict__ eps,
                                float* __restrict__ comb, float* __restrict__ tmpsum)
{
    __shared__ float part[4];
    int t = threadIdx.x; int w = t >> 6, l = t & 63;
    if (t < 4) part[t] = 0.f;
    __syncthreads();
    int b = blockIdx.x * 4 + w;
    const float* xr = xv + (size_t)b * OUT_D;
    float x0 = xr[l], x1 = xr[l + 64];
    float dots[5];
#pragma unroll
    for (int e = 0; e < 4; e++) {
        const float* gw = gate_w + e * OUT_D;
        float v = x0 * gw[l] + x1 * gw[l + 64];
        for (int off = 32; off; off >>= 1) v += __shfl_down(v, off);
        dots[e] = v;
    }
    {
        float v = x0 * noise_w[l] + x1 * noise_w[l + 64];
        for (int off = 32; off; off >>= 1) v += __shfl_down(v, off);
        dots[4] = v;
    }
    if (l == 0) {
        float xg = dots[4];
        float nsd = (xg > 20.f) ? xg : log1pf(expf(xg));
        float hv[4];
#pragma unroll
        for (int e = 0; e < 4; e++) hv[e] = dots[e] + eps[(size_t)b * 4 + e] * nsd;
        int i1 = 0;
        for (int e = 1; e < 4; e++) if (hv[e] < hv[i1]) i1 = e;
        int i2 = -1;
        for (int e = 0; e < 4; e++) { if (e == i1) continue; if (i2 < 0 || hv[e] < hv[i2]) i2 = e; }
        int k1 = -1, k2 = -1;
        for (int e = 0; e < 4; e++) { if (e != i1 && e != i2) { if (k1 < 0) k1 = e; else k2 = e; } }
        float mm = fmaxf(hv[k1], hv[k2]);
        float e1 = expf(hv[k1] - mm), e2 = expf(hv[k2] - mm);
        float s = e1 + e2;
        float L[4] = {0.f, 0.f, 0.f, 0.f};
        L[k1] = e1 / s; L[k2] = e2 / s;
#pragma unroll
        for (int e = 0; e < 4; e++) comb[(size_t)b * 4 + e] = L[e];
        atomicAdd(&part[k1], L[k1]);
        atomicAdd(&part[k2], L[k2]);
    }
    __syncthreads();
    if (t < 4) atomicAdd(&tmpsum[t], part[t]);
}

__global__ void moe_combine_kernel(const float* __restrict__ eo, const float* __restrict__ comb,
                                   float* __restrict__ zout)
{
    int idx = blockIdx.x * blockDim.x + threadIdx.x;
    if (idx >= BB * OUT_D) return;
    int b = idx >> 7, o = idx & 127;
    const size_t S = (size_t)BB * OUT_D;
    float v = comb[b * 4 + 0] * eo[idx] + comb[b * 4 + 1] * eo[idx + S]
            + comb[b * 4 + 2] * eo[idx + 2 * S] + comb[b * 4 + 3] * eo[idx + 3 * S];
    zout[(size_t)b * (3 * OUT_D) + o] = v;
}

__global__ void loss_kernel(const float* __restrict__ tmpsum, float* __restrict__ out)
{
    if (threadIdx.x == 0 && blockIdx.x == 0) {
        float total = 0.f;
        for (int v = 0; v < 3; v++) {
            const float* tp = tmpsum + v * 4;
            float mean = (tp[0] + tp[1] + tp[2] + tp[3]) * 0.25f;
            float var = 0.f;
            for (int e = 0; e < 4; e++) { float d = tp[e] - mean; var += d * d; }
            var /= 3.f;
            float r = sqrtf(var) / mean;
            total += r * r;
        }
        out[0] = total;
    }
}

// ---------------------------------------------------------------------------
// Transformer small kernels
// ---------------------------------------------------------------------------
__global__ void attn_kernel(const float* __restrict__ qkv, float* __restrict__ o)
{
    int t = threadIdx.x;
    int half = t >> 5;
    int d = t & 31;
    int task = blockIdx.x * 8 + half;   // b*4 + h
    int b = task >> 2, h = task & 3;
    const float* base = qkv + (size_t)b * 3 * 384 + h * 32;
    float q0 = base[d],       q1 = base[384 + d],       q2 = base[768 + d];
    float k0 = base[128 + d], k1 = base[384 + 128 + d], k2 = base[768 + 128 + d];
    float v0 = base[256 + d], v1 = base[384 + 256 + d], v2 = base[768 + 256 + d];
    float s[3][3];
    s[0][0] = q0 * k0; s[0][1] = q0 * k1; s[0][2] = q0 * k2;
    s[1][0] = q1 * k0; s[1][1] = q1 * k1; s[1][2] = q1 * k2;
    s[2][0] = q2 * k0; s[2][1] = q2 * k1; s[2][2] = q2 * k2;
#pragma unroll
    for (int i = 0; i < 3; i++)
#pragma unroll
        for (int j = 0; j < 3; j++) {
            float v = s[i][j];
            for (int off = 16; off; off >>= 1) v += __shfl_xor(v, off, 32);
            s[i][j] = v;
        }
    const float scale = 0.17677669529663687f;
    float outv[3];
#pragma unroll
    for (int i = 0; i < 3; i++) {
        float a0 = s[i][0] * scale, a1 = s[i][1] * scale, a2 = s[i][2] * scale;
        float m = fmaxf(a0, fmaxf(a1, a2));
        float e0 = expf(a0 - m), e1 = expf(a1 - m), e2 = expf(a2 - m);
        float inv = 1.f / (e0 + e1 + e2);
        outv[i] = (e0 * v0 + e1 * v1 + e2 * v2) * inv;
    }
    float* ob = o + (size_t)b * 3 * 128 + h * 32;
    ob[d] = outv[0]; ob[128 + d] = outv[1]; ob[256 + d] = outv[2];
}

__global__ void ln_residual_kernel(float* __restrict__ x, const float* __restrict__ add,
                                   const float* __restrict__ g, const float* __restrict__ bta, int M)
{
    int t = threadIdx.x; int w = t >> 6, l = t & 63;
    int row = blockIdx.x * 4 + w; if (row >= M) return;
    float* xr = x + (size_t)row * 128;
    const float* ar = add + (size_t)row * 128;
    float v0 = xr[l] + ar[l], v1 = xr[l + 64] + ar[l + 64];
    float s = v0 + v1;
    for (int off = 32; off; off >>= 1) s += __shfl_down(s, off);
    s = __shfl(s, 0);
    float mu = s * (1.f / 128.f);
    float d0 = v0 - mu, d1 = v1 - mu;
    float q = d0 * d0 + d1 * d1;
    for (int off = 32; off; off >>= 1) q += __shfl_down(q, off);
    q = __shfl(q, 0);
    float inv = rsqrtf(q * (1.f / 128.f) + 1e-5f);
    xr[l]      = d0 * inv * g[l] + bta[l];
    xr[l + 64] = d1 * inv * g[l + 64] + bta[l + 64];
}

__global__ void clf_kernel(const float* __restrict__ z, const float* __restrict__ w,
                           const float* __restrict__ b, float* __restrict__ out)
{
    int t = threadIdx.x; int wv = t >> 6, l = t & 63;
    int row = blockIdx.x * 4 + wv; if (row >= BB) return;
    const float* zr = z + (size_t)row * 384;
    float v0 = 0.f, v1 = 0.f;
    for (int i = l; i < 384; i += 64) {
        float zz = zr[i];
        v0 += zz * w[i];
        v1 += zz * w[384 + i];
    }
    for (int off = 32; off; off >>= 1) { v0 += __shfl_down(v0, off); v1 += __shfl_down(v1, off); }
    if (l == 0) { out[row * 2] = v0 + b[0]; out[row * 2 + 1] = v1 + b[1]; }
}

// ---------------------------------------------------------------------------
// Orchestration
// ---------------------------------------------------------------------------
extern "C" void kernel_launch(void* const* d_in, const int* in_sizes, int n_in,
                              void* d_out, int out_size, void* d_ws, size_t ws_size,
                              hipStream_t stream)
{
    const float* x         = (const float*)d_in[0];
    const float* noise     = (const float*)d_in[1];
    const float* g_lin1_w  = (const float*)d_in[2];
    const float* g_lin1_b  = (const float*)d_in[3];
    const float* conv_W    = (const float*)d_in[4];
    const float* conv_Wr   = (const float*)d_in[5];
    const float* conv_a    = (const float*)d_in[6];
    const float* conv_Wres = (const float*)d_in[7];
    const float* conv_rel  = (const float*)d_in[8];
    const float* g_lin2_w  = (const float*)d_in[9];
    const float* g_lin2_b  = (const float*)d_in[10];
    const float* te_w      = (const float*)d_in[11];
    const float* te_b      = (const float*)d_in[12];
    const float* me_w1     = (const float*)d_in[13];
    const float* me_b1     = (const float*)d_in[14];
    const float* me_w2     = (const float*)d_in[15];
    const float* me_b2     = (const float*)d_in[16];
    const float* moe_gate_w  = (const float*)d_in[17];
    const float* moe_noise_w = (const float*)d_in[18];
    const float* moe_w1    = (const float*)d_in[19];
    const float* moe_b1    = (const float*)d_in[20];
    const float* moe_w2    = (const float*)d_in[21];
    const float* moe_b2    = (const float*)d_in[22];
    const float* tf_qkv_w  = (const float*)d_in[23];
    const float* tf_qkv_b  = (const float*)d_in[24];
    const float* tf_out_w  = (const float*)d_in[25];
    const float* tf_out_b  = (const float*)d_in[26];
    const float* tf_ln1_g  = (const float*)d_in[27];
    const float* tf_ln1_b  = (const float*)d_in[28];
    const float* tf_ff1_w  = (const float*)d_in[29];
    const float* tf_ff1_b  = (const float*)d_in[30];
    const float* tf_ff2_w  = (const float*)d_in[31];
    const float* tf_ff2_b  = (const float*)d_in[32];
    const float* tf_ln2_g  = (const float*)d_in[33];
    const float* tf_ln2_b  = (const float*)d_in[34];
    const float* clf_w     = (const float*)d_in[35];
    const float* clf_b     = (const float*)d_in[36];
    const int*   edge_index = (const int*)d_in[37];
    const int*   edge_type  = (const int*)d_in[38];

    float* ws = (float*)d_ws;

    // Arena (float offsets)
    const size_t F_A = 0;
    const size_t F_B = 10240000;
    const size_t F_C = 22822912;
    const size_t F_D = 33062912;
    const size_t F_M = 43302912;
    const size_t F_X = 44200000;   // bf16 split region

    float* h0     = ws + F_A;
    float* qkv    = ws + F_A;
    float* wx     = ws + F_B;
    float* graph  = ws + F_B;
    ushort* ff1bf = (ushort*)(ws + F_B);
    float* agg    = ws + F_C;
    float* x_mh   = ws + F_C;
    ushort* h1bf  = (ushort*)(ws + F_C);
    float* attn_o = ws + F_C;
    float* tmp1   = ws + F_C + 3200000;
    float* hl1    = ws + F_D;
    float* z      = ws + F_D;
    float* x_t    = ws + F_D + 3200000;
    float* x_m    = ws + F_D + 4300000;
    float* eo     = ws + F_D + 5400000;

    float* s_i    = ws + F_M;
    float* s_j    = ws + F_M + 40000;
    float* rsv    = ws + F_M + 80000;
    float* comb   = ws + F_M + 80016;
    float* tmpsum = ws + F_M + 112784;
    int* deg      = (int*)(ws + F_M + 120000);
    int* rowstart = (int*)(ws + F_M + 161000);
    int* cursor   = (int*)(ws + F_M + 202000);
    unsigned* csr_val = (unsigned*)(ws + F_M + 242000);

    // split-bf16 buffers (ushort)
    ushort* xhi = (ushort*)(ws + F_X);                    // 40000x800
    ushort* xlo = (ushort*)(ws + F_X + 16000000);
    ushort* hhi = (ushort*)(ws + F_X + 32000000);         // 40000x256
    ushort* hlo = (ushort*)(ws + F_X + 37120000);
    ushort* wbh = (ushort*)(ws + F_X + 42240000);         // up to 256x800
    ushort* wbl = (ushort*)(ws + F_X + 42342400);

    const int* srcv = edge_index;
    const int* dstv = edge_index + EE;

    // ---- 0. CSR build ----
    hipMemsetAsync(deg, 0, NN * sizeof(int), stream);
    deg_kernel<<<(EE + 255) / 256, 256, 0, stream>>>(dstv, deg);
    scan_kernel<<<1, 1024, 0, stream>>>(deg, rowstart, cursor, NN);
    fill_kernel<<<(EE + 255) / 256, 256, 0, stream>>>(srcv, dstv, edge_type, cursor, csr_val);

    // ---- 1. h = relu(x @ g_lin1_w.T + b) via split-bf16 MFMA ----
    cvt(x, XDIM, XDIM, xhi, xlo, NN, 800, stream);
    cvt(g_lin1_w, XDIM, XDIM, wbh, wbl, HID, 800, stream);
    mfma3_launch<1, 0>(xhi, xlo, 800, wbh, wbl, 800, g_lin1_b, nullptr, h0,
                       NN, HID, 800, stream);

    // ---- 2. two HGN layers ----
    float* hin = h0;
    float* hout = hl1;
    for (int layer = 0; layer < 2; layer++) {
        const float* W    = conv_W    + (size_t)layer * HID * HID;
        const float* Wr   = conv_Wr   + (size_t)layer * HID * REL_D;
        const float* a    = conv_a    + (size_t)layer * 3 * HID;
        const float* Wres = conv_Wres + (size_t)layer * HID * HID;
        const float* rel  = conv_rel  + (size_t)layer * NET_T * REL_D;

        cvt(hin, HID, HID, hhi, hlo, NN, HID, stream);
        cvt(W, HID, HID, wbh, wbl, HID, HID, stream);
        mfma3_launch<0, 0>(hhi, hlo, HID, wbh, wbl, HID, nullptr, nullptr, wx,
                           NN, HID, HID, stream);
        sisj_kernel<<<NN / 4, 256, 0, stream>>>(wx, a, s_i, s_j, NN);
        rs_kernel<<<NET_T, 256, 0, stream>>>(Wr, rel, a + 2 * HID, rsv);
        csr_agg_kernel<<<NN / 4, 256, 0, stream>>>(csr_val, rowstart, s_i, s_j, rsv, wx, agg);
        cvt(Wres, HID, HID, wbh, wbl, HID, HID, stream);
        mfma3_launch<2, 1>(hhi, hlo, HID, wbh, wbl, HID, nullptr, agg, hout,
                           NN, HID, HID, stream);
        if (layer == 1) rownorm_kernel<<<NN / 4, 256, 0, stream>>>(hout, NN);
        float* t2 = hin; hin = hout; hout = t2;
    }
    float* h2 = hin;

    // ---- 3. graph = relu(h2 @ g_lin2.T + b) ----
    cvt(h2, HID, HID, hhi, hlo, NN, HID, stream);
    cvt(g_lin2_w, HID, HID, wbh, wbl, OUT_D, HID, stream);
    mfma3_launch<1, 0>(hhi, hlo, HID, wbh, wbl, HID, g_lin2_b, nullptr, graph,
                       NN, OUT_D, HID, stream);

    // ---- 4. view encoders ----
    cvt(te_w, IN_DIM, IN_DIM, wbh, wbl, OUT_D, IN_DIM, stream);
    mfma3_launch<1, 0>(xhi, xlo, 800, wbh, wbl, IN_DIM, te_b, nullptr, x_t,
                       BB, OUT_D, IN_DIM, stream);
    launch_gemm(1, x + IN_DIM, XDIM, me_w1, me_b1, nullptr, x_mh, BB, HID, META_DIM, stream);
    launch_gemm(1, x_mh, HID, me_w2, me_b2, nullptr, x_m, BB, OUT_D, HID, stream);

    // ---- 5. MoE per view: fp32 gate, bf16 MFMA experts ----
    hipMemsetAsync(tmpsum, 0, 16 * sizeof(float), stream);
    const float* xvs[3] = { graph, x_t, x_m };
    for (int v = 0; v < 3; v++) {
        const float* xv = xvs[v];
        moe_gate_kernel<<<BB / 4, 256, 0, stream>>>(
            xv, moe_gate_w + (size_t)v * NEXP * OUT_D, moe_noise_w + (size_t)v * OUT_D,
            noise + (size_t)v * BB * NEXP, comb, tmpsum + v * 4);
        mfma_launch<1, 0, 1>(xv, 0,
                             moe_w1 + (size_t)v * 4 * FF_D * OUT_D, (size_t)FF_D * OUT_D,
                             moe_b1 + (size_t)v * 4 * FF_D, FF_D,
                             h1bf, (size_t)BB * FF_D,
                             BB, FF_D, OUT_D, 4, stream);
        mfma_launch<0, 1, 0>(h1bf, (size_t)BB * FF_D,
                             moe_w2 + (size_t)v * 4 * OUT_D * FF_D, (size_t)OUT_D * FF_D,
                             moe_b2 + (size_t)v * 4 * OUT_D, OUT_D,
                             eo, (size_t)BB * OUT_D,
                             BB, OUT_D, FF_D, 4, stream);
        moe_combine_kernel<<<(BB * OUT_D) / 256, 256, 0, stream>>>(eo, comb, z + v * OUT_D);
    }

    // ---- 6. transformer x4 on z (24576,128) ----
    const int MT = BB * 3;
    for (int li = 0; li < NLAY; li++) {
        mfma_launch<0, 0, 0>(z, 0, tf_qkv_w + (size_t)li * 384 * 128, 0,
                             tf_qkv_b + li * 384, 0, qkv, 0, MT, 384, 128, 1, stream);
        attn_kernel<<<(BB * 4) / 8, 256, 0, stream>>>(qkv, attn_o);
        mfma_launch<0, 0, 0>(attn_o, 0, tf_out_w + (size_t)li * 128 * 128, 0,
                             tf_out_b + li * 128, 0, tmp1, 0, MT, 128, 128, 1, stream);
        ln_residual_kernel<<<MT / 4, 256, 0, stream>>>(z, tmp1, tf_ln1_g + li * 128, tf_ln1_b + li * 128, MT);
        mfma_launch<1, 0, 1>(z, 0, tf_ff1_w + (size_t)li * 512 * 128, 0,
                             tf_ff1_b + li * 512, 0, ff1bf, 0, MT, 512, 128, 1, stream);
        mfma_launch<0, 1, 0>(ff1bf, 0, tf_ff2_w + (size_t)li * 128 * 512, 0,
                             tf_ff2_b + li * 128, 0, tmp1, 0, MT, 128, 512, 1, stream);
        ln_residual_kernel<<<MT / 4, 256, 0, stream>>>(z, tmp1, tf_ln2_g + li * 128, tf_ln2_b + li * 128, MT);
    }

    // ---- 7. classifier + loss ----
    clf_kernel<<<BB / 4, 256, 0, stream>>>(z, clf_w, clf_b, (float*)d_out);
    loss_kernel<<<1, 64, 0, stream>>>(tmpsum, (float*)d_out + BB * 2);
}